// Round 10
// baseline (501.786 us; speedup 1.0000x reference)
//
#include <hip/hip_runtime.h>

#define NN 100000
#define NE 1600000
#define NG 512
#define NPARTS 500    // dst partitions
#define PW 200        // partition width (500*200 = 100000)
#define NCHUNKS 128   // edge chunks
#define CE 12500      // edges per chunk (128*12500 = 1.6M)
#define NCNT (NPARTS * NCHUNKS)

typedef unsigned int uint;
typedef unsigned short ushort;
typedef __bf16 bf16x8 __attribute__((ext_vector_type(8)));
typedef float f32x4 __attribute__((ext_vector_type(4)));

// ---- bf16 pack helpers (round-to-nearest-even) ----
__device__ inline uint f2bf2(float a, float b) {
  uint ua = __float_as_uint(a), ub = __float_as_uint(b);
  ua += 0x7fff + ((ua >> 16) & 1);
  ub += 0x7fff + ((ub >> 16) & 1);
  return (ua >> 16) | (ub & 0xffff0000u);
}
__device__ inline ushort f2bf(float f) {
  uint u = __float_as_uint(f);
  u += 0x7fff + ((u >> 16) & 1);
  return (ushort)(u >> 16);
}
__device__ inline float2 bf2f(uint v) {
  float2 r;
  r.x = __uint_as_float(v << 16);
  r.y = __uint_as_float(v & 0xffff0000u);
  return r;
}
__device__ inline uint relu2(uint u) {
  uint lo = (u & 0x8000u) ? 0u : (u & 0xFFFFu);
  uint hi = (u & 0x80000000u) ? 0u : (u & 0xFFFF0000u);
  return lo | hi;
}

// ---------------- prep: weight transposes (blocks 0..191) + bucket_count (192..319) ----------------
__global__ __launch_bounds__(256) void prep(const float* __restrict__ W1, uint* __restrict__ w1t,
                                            const float* __restrict__ W2, uint* __restrict__ w2t,
                                            const int* __restrict__ dst, int* __restrict__ cnt) {
  int b = blockIdx.x, t = threadIdx.x;
  if (b < 192) {
    __shared__ float col[256];
    const float* W; uint* Wt; int K, N, n;
    if (b < 128) { W = W1; Wt = w1t; K = 256; N = 128; n = b; }
    else         { W = W2; Wt = w2t; K = 128; N = 64;  n = b - 128; }
    if (t < K) col[t] = W[(size_t)t * N + n];
    __syncthreads();
    if (t < K / 2) Wt[(size_t)n * (K / 2) + t] = f2bf2(col[2 * t], col[2 * t + 1]);
  } else {
    __shared__ int h[NPARTS];
    int c = b - 192;
    for (int i = t; i < NPARTS; i += 256) h[i] = 0;
    __syncthreads();
    int beg = c * CE;
    for (int j = t; j < CE; j += 256) atomicAdd(&h[dst[beg + j] / PW], 1);
    __syncthreads();
    for (int i = t; i < NPARTS; i += 256) cnt[i * NCHUNKS + c] = h[i];
  }
}

// ---------------- scan (block-local exclusive; bsum added at consumer) ----------------
__global__ void scan1(const int* __restrict__ in, int* __restrict__ out,
                      int* __restrict__ bsum, int n) {
  __shared__ int s[256];
  int t = threadIdx.x;
  int i = blockIdx.x * 256 + t;
  int v = (i < n) ? in[i] : 0;
  s[t] = v;
  __syncthreads();
  for (int off = 1; off < 256; off <<= 1) {
    int add = (t >= off) ? s[t - off] : 0;
    __syncthreads();
    s[t] += add;
    __syncthreads();
  }
  if (i < n) out[i] = s[t] - v;
  if (t == 255) bsum[blockIdx.x] = s[255];
}

__global__ void scan2(int* __restrict__ bsum, int nb) {
  __shared__ int s[512];
  int t = threadIdx.x;
  int v = (t < nb) ? bsum[t] : 0;
  s[t] = v;
  __syncthreads();
  for (int off = 1; off < 512; off <<= 1) {
    int add = (t >= off) ? s[t - off] : 0;
    __syncthreads();
    s[t] += add;
    __syncthreads();
  }
  if (t < nb) bsum[t] = s[t] - v;
}

// ---------------- bucket scatter (global offsets = off + bsum) ----------------
__global__ __launch_bounds__(256) void bucket_scatter(const int* __restrict__ src,
                                                      const int* __restrict__ dst,
                                                      const int* __restrict__ off,
                                                      const int* __restrict__ bsum,
                                                      uint* __restrict__ pk) {
  __shared__ int cur[NPARTS];
  int t = threadIdx.x, c = blockIdx.x;
  for (int i = t; i < NPARTS; i += 256) {
    int idx = i * NCHUNKS + c;
    cur[i] = off[idx] + bsum[idx >> 8];
  }
  __syncthreads();
  int beg = c * CE;
  for (int j = t; j < CE; j += 256) {
    int d = dst[beg + j];
    int p = d / PW;
    int pos = atomicAdd(&cur[p], 1);
    pk[pos] = (uint)src[beg + j] | ((uint)(d - p * PW) << 17);
  }
}

__global__ __launch_bounds__(256) void csr_finalize(const uint* __restrict__ pk,
                                                    const int* __restrict__ off,
                                                    const int* __restrict__ bsum,
                                                    int* __restrict__ row_off,
                                                    float* __restrict__ dinv,
                                                    int* __restrict__ csr) {
  __shared__ int hist[PW];
  __shared__ int cur[PW];
  __shared__ int s[256];
  int p = blockIdx.x, t = threadIdx.x;
  int idx0 = p * NCHUNKS;
  int base = off[idx0] + bsum[idx0 >> 8];
  int endp = NE;
  if (p < NPARTS - 1) {
    int idx1 = (p + 1) * NCHUNKS;
    endp = off[idx1] + bsum[idx1 >> 8];
  }
  if (t < PW) hist[t] = 0;
  __syncthreads();
  for (int j = base + t; j < endp; j += 256) atomicAdd(&hist[pk[j] >> 17], 1);
  __syncthreads();
  int v = (t < PW) ? hist[t] : 0;
  s[t] = v;
  __syncthreads();
  for (int o = 1; o < 256; o <<= 1) {
    int add = (t >= o) ? s[t - o] : 0;
    __syncthreads();
    s[t] += add;
    __syncthreads();
  }
  if (t < PW) {
    int excl = base + (s[t] - v);
    int node = p * PW + t;
    row_off[node] = excl;
    dinv[node]    = rsqrtf((float)v + 1.0f);
    cur[t] = excl;
  }
  if (p == NPARTS - 1 && t == 0) row_off[NN] = NE;
  __syncthreads();
  for (int j = base + t; j < endp; j += 256) {
    uint e = pk[j];
    int pos = atomicAdd(&cur[e >> 17], 1);
    csr[pos] = (int)(e & 0x1FFFFu);
  }
}

// ---------------- barrier-free skinny MFMA GEMM ----------------
template<int K, int N, int WM, int WN, int A_BF16, int RELU>
__global__ __launch_bounds__(256) void gemm_direct(const void* __restrict__ Av,
                                                   const uint* __restrict__ Bt,
                                                   const float* __restrict__ dinv,
                                                   ushort* __restrict__ Cb, int M) {
  constexpr int NW = N / WN;     // cols per wave
  constexpr int NT = NW / 16;    // b-frags per wave
  __shared__ __align__(16) char bsm[N * K * 2];
  const int tid  = threadIdx.x;
  const int wid  = tid >> 6;
  const int lane = tid & 63;
  const int wm   = wid % WM;
  const int wn   = wid / WM;
  const int l15  = lane & 15;
  const int lk   = lane >> 4;
  const int blockRow = blockIdx.x * (WM * 32);

  constexpr int UPR = K / 8;        // uint4 per B row
  constexpr int TOT = N * K / 8;    // total uint4
#pragma unroll
  for (int i0 = 0; i0 < TOT; i0 += 256) {
    int i = i0 + tid;
    uint4 v = reinterpret_cast<const uint4*>(Bt)[i];
    int n = i / UPR, c = i % UPR;
    int byte = (n * (K * 2) + c * 16) ^ ((n & 7) << 4);
    *reinterpret_cast<uint4*>(bsm + byte) = v;
  }
  __syncthreads();

  f32x4 acc[2][NT];
#pragma unroll
  for (int i = 0; i < 2; ++i)
#pragma unroll
    for (int j = 0; j < NT; ++j) acc[i][j] = (f32x4){0.f, 0.f, 0.f, 0.f};

#pragma unroll
  for (int kk = 0; kk < K / 32; ++kk) {
    bf16x8 af[2], bfr[NT];
#pragma unroll
    for (int mt = 0; mt < 2; ++mt) {
      int grow = blockRow + wm * 32 + mt * 16 + l15;
      int row = grow < M ? grow : M - 1;
      if (A_BF16) {
        uint4 va = *reinterpret_cast<const uint4*>((const uint*)Av + (size_t)row * (K / 2) + kk * 16 + lk * 4);
        if (RELU) { va.x = relu2(va.x); va.y = relu2(va.y); va.z = relu2(va.z); va.w = relu2(va.w); }
        af[mt] = __builtin_bit_cast(bf16x8, va);
      } else {
        const float4* p = reinterpret_cast<const float4*>((const float*)Av + (size_t)row * K + kk * 32 + lk * 8);
        float4 f0 = p[0], f1 = p[1];
        uint4 va;
        va.x = f2bf2(f0.x, f0.y); va.y = f2bf2(f0.z, f0.w);
        va.z = f2bf2(f1.x, f1.y); va.w = f2bf2(f1.z, f1.w);
        af[mt] = __builtin_bit_cast(bf16x8, va);
      }
    }
#pragma unroll
    for (int nt = 0; nt < NT; ++nt) {
      int n = wn * NW + nt * 16 + l15;
      int byte = (n * (K * 2) + kk * 64 + lk * 16) ^ ((n & 7) << 4);
      bfr[nt] = __builtin_bit_cast(bf16x8, *reinterpret_cast<uint4*>(bsm + byte));
    }
#pragma unroll
    for (int mt = 0; mt < 2; ++mt)
#pragma unroll
      for (int nt = 0; nt < NT; ++nt)
        acc[mt][nt] = __builtin_amdgcn_mfma_f32_16x16x32_bf16(af[mt], bfr[nt], acc[mt][nt], 0, 0, 0);
  }

#pragma unroll
  for (int mt = 0; mt < 2; ++mt) {
    int rbase = blockRow + wm * 32 + mt * 16 + lk * 4;
#pragma unroll
    for (int j = 0; j < 4; ++j) {
      int grow = rbase + j;
      if (grow < M) {
        float d = dinv[grow];
#pragma unroll
        for (int nt = 0; nt < NT; ++nt) {
          int gcol = wn * NW + nt * 16 + l15;
          Cb[(size_t)grow * N + gcol] = f2bf(acc[mt][nt][j] * d);
        }
      }
    }
  }
}

// ---------------- conv1 agg, column-sliced (XCD-local L2 gather) ----------------
// grid = (NN/32) * 8; grp = blockIdx&7 -> col group (2 uint4 = 32B of each row).
// Wave: 8 nodes x 4 edge slots x 2 cols. Per-XCD slice = 3.2 MB (L2-resident).
__global__ __launch_bounds__(256) void agg_f128_sliced(const uint4* __restrict__ hs,
                                                       const float* __restrict__ dinv,
                                                       const float* __restrict__ bias,
                                                       const int* __restrict__ row_off,
                                                       const int* __restrict__ csr,
                                                       uint4* __restrict__ outb) {
  int grp   = blockIdx.x & 7;
  int chunk = blockIdx.x >> 3;               // 0..3124
  int wid   = threadIdx.x >> 6;
  int lane  = threadIdx.x & 63;
  int node  = chunk * 32 + wid * 8 + (lane >> 3);
  int sl    = (lane >> 1) & 3;               // edge slot 0..3
  int cc    = lane & 1;                      // uint4 within group
  int c4    = grp * 2 + cc;                  // uint4 column 0..15
  int beg = row_off[node], end = row_off[node + 1];
  float a0=0,a1=0,a2=0,a3=0,a4=0,a5=0,a6=0,a7=0;
  for (int j = beg + sl; j < end; j += 4) {
    int s = csr[j];
    uint4 v = hs[(size_t)s * 16 + c4];
    float2 f;
    f = bf2f(v.x); a0+=f.x; a1+=f.y;  f = bf2f(v.y); a2+=f.x; a3+=f.y;
    f = bf2f(v.z); a4+=f.x; a5+=f.y;  f = bf2f(v.w); a6+=f.x; a7+=f.y;
  }
  // reduce across 4 slots (lane bits 1,2)
  a0 += __shfl_xor(a0, 2); a1 += __shfl_xor(a1, 2); a2 += __shfl_xor(a2, 2); a3 += __shfl_xor(a3, 2);
  a4 += __shfl_xor(a4, 2); a5 += __shfl_xor(a5, 2); a6 += __shfl_xor(a6, 2); a7 += __shfl_xor(a7, 2);
  a0 += __shfl_xor(a0, 4); a1 += __shfl_xor(a1, 4); a2 += __shfl_xor(a2, 4); a3 += __shfl_xor(a3, 4);
  a4 += __shfl_xor(a4, 4); a5 += __shfl_xor(a5, 4); a6 += __shfl_xor(a6, 4); a7 += __shfl_xor(a7, 4);
  if (sl == 0) {
    uint4 v = hs[(size_t)node * 16 + c4];  // self
    float2 f;
    f = bf2f(v.x); a0+=f.x; a1+=f.y;  f = bf2f(v.y); a2+=f.x; a3+=f.y;
    f = bf2f(v.z); a4+=f.x; a5+=f.y;  f = bf2f(v.w); a6+=f.x; a7+=f.y;
    float d = dinv[node];
    const float4* bp = reinterpret_cast<const float4*>(bias);
    float4 b0 = bp[c4 * 2], b1 = bp[c4 * 2 + 1];
    uint4 o;
    o.x = f2bf2(fmaf(a0, d, b0.x), fmaf(a1, d, b0.y));
    o.y = f2bf2(fmaf(a2, d, b0.z), fmaf(a3, d, b0.w));
    o.z = f2bf2(fmaf(a4, d, b1.x), fmaf(a5, d, b1.y));
    o.w = f2bf2(fmaf(a6, d, b1.z), fmaf(a7, d, b1.w));
    outb[(size_t)node * 16 + c4] = o;
  }
}

// ---------------- conv2 agg, column-sliced; f32 out, b2 deferred ----------------
// grid = (NN/32) * 8; grp -> 1 uint4 (16B) of each 128B row. Per-XCD slice = 1.6 MB.
// Wave: 8 nodes x 8 edge slots.
__global__ __launch_bounds__(256) void agg_f64_sliced(const uint4* __restrict__ hs,
                                                      const float* __restrict__ dinv,
                                                      const int* __restrict__ row_off,
                                                      const int* __restrict__ csr,
                                                      float* __restrict__ out) {
  int grp   = blockIdx.x & 7;
  int chunk = blockIdx.x >> 3;
  int wid   = threadIdx.x >> 6;
  int lane  = threadIdx.x & 63;
  int node  = chunk * 32 + wid * 8 + (lane >> 3);
  int sl    = lane & 7;                      // edge slot 0..7
  int beg = row_off[node], end = row_off[node + 1];
  float a0=0,a1=0,a2=0,a3=0,a4=0,a5=0,a6=0,a7=0;
  for (int j = beg + sl; j < end; j += 8) {
    int s = csr[j];
    uint4 v = hs[(size_t)s * 8 + grp];
    float2 f;
    f = bf2f(v.x); a0+=f.x; a1+=f.y;  f = bf2f(v.y); a2+=f.x; a3+=f.y;
    f = bf2f(v.z); a4+=f.x; a5+=f.y;  f = bf2f(v.w); a6+=f.x; a7+=f.y;
  }
  // reduce across 8 slots (lane bits 0,1,2)
  a0 += __shfl_xor(a0, 1); a1 += __shfl_xor(a1, 1); a2 += __shfl_xor(a2, 1); a3 += __shfl_xor(a3, 1);
  a4 += __shfl_xor(a4, 1); a5 += __shfl_xor(a5, 1); a6 += __shfl_xor(a6, 1); a7 += __shfl_xor(a7, 1);
  a0 += __shfl_xor(a0, 2); a1 += __shfl_xor(a1, 2); a2 += __shfl_xor(a2, 2); a3 += __shfl_xor(a3, 2);
  a4 += __shfl_xor(a4, 2); a5 += __shfl_xor(a5, 2); a6 += __shfl_xor(a6, 2); a7 += __shfl_xor(a7, 2);
  a0 += __shfl_xor(a0, 4); a1 += __shfl_xor(a1, 4); a2 += __shfl_xor(a2, 4); a3 += __shfl_xor(a3, 4);
  a4 += __shfl_xor(a4, 4); a5 += __shfl_xor(a5, 4); a6 += __shfl_xor(a6, 4); a7 += __shfl_xor(a7, 4);
  if (sl == 0) {
    uint4 v = hs[(size_t)node * 8 + grp];  // self
    float2 f;
    f = bf2f(v.x); a0+=f.x; a1+=f.y;  f = bf2f(v.y); a2+=f.x; a3+=f.y;
    f = bf2f(v.z); a4+=f.x; a5+=f.y;  f = bf2f(v.w); a6+=f.x; a7+=f.y;
    float d = dinv[node];
    float4* op = reinterpret_cast<float4*>(out + (size_t)node * 64 + grp * 8);
    op[0] = make_float4(a0 * d, a1 * d, a2 * d, a3 * d);
    op[1] = make_float4(a4 * d, a5 * d, a6 * d, a7 * d);
  }
}

// ---------------- fused per-graph mean pool + MLP (adds deferred b2) ----------------
__global__ __launch_bounds__(256) void pool_mlp(const float* __restrict__ h,
                                                const int* __restrict__ batch,
                                                const float* __restrict__ scalars,
                                                const float* __restrict__ b2,
                                                const float* __restrict__ W3,
                                                const float* __restrict__ b3,
                                                const float* __restrict__ W4,
                                                const float* __restrict__ b4,
                                                float* __restrict__ out, int N) {
  int g = blockIdx.x;
  int t = threadIdx.x;  // 256
  int col = t & 63, rr = t >> 6;
  __shared__ int range[2];
  __shared__ float part[4][64];
  __shared__ float comb[66];
  __shared__ float red[2];
  if (t < 2) {
    int target = g + t;
    int lo = 0, hi = N;
    while (lo < hi) { int mid = (lo + hi) >> 1; if (batch[mid] < target) lo = mid + 1; else hi = mid; }
    range[t] = lo;
  }
  __syncthreads();
  int beg = range[0], end = range[1];
  float s = 0.f;
  for (int i = beg + rr; i < end; i += 4) s += h[(size_t)i * 64 + col];
  part[rr][col] = s;
  __syncthreads();
  if (rr == 0) {
    float tot = (part[0][col] + part[1][col]) + (part[2][col] + part[3][col]);
    comb[col] = tot / fmaxf((float)(end - beg), 1.f) + b2[col];
  } else if (t == 64 || t == 65) {
    comb[t] = scalars[g * 2 + (t - 64)];
  }
  __syncthreads();
  if (t < 128) {
    float hh = b3[t];
#pragma unroll
    for (int k = 0; k < 66; ++k) hh += comb[k] * W3[k * 128 + t];
    hh = fmaxf(hh, 0.f);
    float p = hh * W4[t];
#pragma unroll
    for (int off = 32; off > 0; off >>= 1) p += __shfl_down(p, off);
    if ((t & 63) == 0) red[t >> 6] = p;
  }
  __syncthreads();
  if (t == 0) {
    float sum = red[0] + red[1] + b4[0];
    out[g] = 1.f / (1.f + expf(-sum));
  }
}

extern "C" void kernel_launch(void* const* d_in, const int* in_sizes, int n_in,
                              void* d_out, int out_size, void* d_ws, size_t ws_size,
                              hipStream_t stream) {
  const float* x       = (const float*)d_in[0];
  const int*   ei      = (const int*)d_in[1];
  const int*   src     = ei;
  const int*   dstp    = ei + NE;
  const int*   batch   = (const int*)d_in[2];
  const float* scalars = (const float*)d_in[3];
  const float* W1 = (const float*)d_in[4];  const float* b1 = (const float*)d_in[5];
  const float* W2 = (const float*)d_in[6];  const float* b2 = (const float*)d_in[7];
  const float* W3 = (const float*)d_in[8];  const float* b3 = (const float*)d_in[9];
  const float* W4 = (const float*)d_in[10]; const float* b4 = (const float*)d_in[11];
  float* out = (float*)d_out;

  // workspace layout (32-bit words) — 16B-aligned segments first
  uint*  ws      = (uint*)d_ws;
  uint*  w1t     = ws;                      // [128*128]  (W1^T bf16)
  uint*  w2t     = ws + 16384;              // [64*64]    (W2^T bf16)
  uint*  hsb     = ws + 20480;              // [100000,64]u bf16 hs; reused [100000,32]u
  uint*  agg1b   = hsb + 6400000;           // [100000,64]u bf16 agg1; reused agg2 f32 [100000,64]
  float* dinv    = (float*)(agg1b + 6400000); // [100000]
  int*   row_off = (int*)(dinv + NN);       // [100004] (padded)
  int*   csr     = row_off + NN + 4;        // [1600000]
  uint*  pk      = (uint*)(csr + NE);       // [1600000]
  int*   cnt     = (int*)(pk + NE);         // [64000]
  int*   bsum    = cnt + NCNT;              // [512]

  // prep: weight transposes + bucket counts (independent, one launch)
  prep<<<320, 256, 0, stream>>>(W1, w1t, W2, w2t, dstp, cnt);

  // CSR build (no global atomics); scan3 folded into consumers
  scan1<<<(NCNT + 255) / 256, 256, 0, stream>>>(cnt, cnt, bsum, NCNT);
  scan2<<<1, 512, 0, stream>>>(bsum, (NCNT + 255) / 256);
  bucket_scatter<<<NCHUNKS, 256, 0, stream>>>(src, dstp, cnt, bsum, pk);
  csr_finalize<<<NPARTS, 256, 0, stream>>>(pk, cnt, bsum, row_off, dinv, csr);

  // conv1: hsb = bf16((x @ W1) * dinv) ; agg1b = bf16(dinv*(gather+self) + b1)
  gemm_direct<256, 128, 4, 1, 0, 0><<<(NN + 127) / 128, 256, 0, stream>>>(
      x, w1t, dinv, (ushort*)hsb, NN);
  agg_f128_sliced<<<(NN / 32) * 8, 256, 0, stream>>>((const uint4*)hsb, dinv, b1,
                                                     row_off, csr, (uint4*)agg1b);

  // conv2: hsb = bf16((relu(agg1b) @ W2) * dinv) ; agg2 = dinv*(gather+self) (f32, b2 deferred)
  gemm_direct<128, 64, 4, 1, 1, 1><<<(NN + 127) / 128, 256, 0, stream>>>(
      agg1b, w2t, dinv, (ushort*)hsb, NN);
  agg_f64_sliced<<<(NN / 32) * 8, 256, 0, stream>>>((const uint4*)hsb, dinv,
                                                    row_off, csr, (float*)agg1b);

  // fused pool + MLP (b2 added here)
  pool_mlp<<<NG, 256, 0, stream>>>((const float*)agg1b, batch, scalars, b2,
                                   W3, b3, W4, b4, out, NN);
}

// Round 11
// 227.681 us; speedup vs baseline: 2.2039x; 2.2039x over previous
//
#include <hip/hip_runtime.h>

#define NN 100000
#define NE 1600000
#define NG 512
#define NPARTS 500    // dst partitions
#define PW 200        // partition width (500*200 = 100000)
#define NCHUNKS 128   // edge chunks
#define CE 12500      // edges per chunk (128*12500 = 1.6M)
#define NCNT (NPARTS * NCHUNKS)

typedef unsigned int uint;
typedef unsigned short ushort;
typedef __bf16 bf16x8 __attribute__((ext_vector_type(8)));
typedef float f32x4 __attribute__((ext_vector_type(4)));

// ---- bf16 pack helpers (round-to-nearest-even) ----
__device__ inline uint f2bf2(float a, float b) {
  uint ua = __float_as_uint(a), ub = __float_as_uint(b);
  ua += 0x7fff + ((ua >> 16) & 1);
  ub += 0x7fff + ((ub >> 16) & 1);
  return (ua >> 16) | (ub & 0xffff0000u);
}
__device__ inline ushort f2bf(float f) {
  uint u = __float_as_uint(f);
  u += 0x7fff + ((u >> 16) & 1);
  return (ushort)(u >> 16);
}
__device__ inline float2 bf2f(uint v) {
  float2 r;
  r.x = __uint_as_float(v << 16);
  r.y = __uint_as_float(v & 0xffff0000u);
  return r;
}
__device__ inline uint relu2(uint u) {
  uint lo = (u & 0x8000u) ? 0u : (u & 0xFFFFu);
  uint hi = (u & 0x80000000u) ? 0u : (u & 0xFFFF0000u);
  return lo | hi;
}

// ---------------- prep: weight transposes (blocks 0..191) + bucket_count (192..319) ----------------
__global__ __launch_bounds__(256) void prep(const float* __restrict__ W1, uint* __restrict__ w1t,
                                            const float* __restrict__ W2, uint* __restrict__ w2t,
                                            const int* __restrict__ dst, int* __restrict__ cnt) {
  int b = blockIdx.x, t = threadIdx.x;
  if (b < 192) {
    __shared__ float col[256];
    const float* W; uint* Wt; int K, N, n;
    if (b < 128) { W = W1; Wt = w1t; K = 256; N = 128; n = b; }
    else         { W = W2; Wt = w2t; K = 128; N = 64;  n = b - 128; }
    if (t < K) col[t] = W[(size_t)t * N + n];
    __syncthreads();
    if (t < K / 2) Wt[(size_t)n * (K / 2) + t] = f2bf2(col[2 * t], col[2 * t + 1]);
  } else {
    __shared__ int h[NPARTS];
    int c = b - 192;
    for (int i = t; i < NPARTS; i += 256) h[i] = 0;
    __syncthreads();
    int beg = c * CE;
    for (int j = t; j < CE; j += 256) atomicAdd(&h[dst[beg + j] / PW], 1);
    __syncthreads();
    for (int i = t; i < NPARTS; i += 256) cnt[i * NCHUNKS + c] = h[i];
  }
}

// ---------------- scan (block-local exclusive; bsum added at consumer) ----------------
__global__ void scan1(const int* __restrict__ in, int* __restrict__ out,
                      int* __restrict__ bsum, int n) {
  __shared__ int s[256];
  int t = threadIdx.x;
  int i = blockIdx.x * 256 + t;
  int v = (i < n) ? in[i] : 0;
  s[t] = v;
  __syncthreads();
  for (int off = 1; off < 256; off <<= 1) {
    int add = (t >= off) ? s[t - off] : 0;
    __syncthreads();
    s[t] += add;
    __syncthreads();
  }
  if (i < n) out[i] = s[t] - v;
  if (t == 255) bsum[blockIdx.x] = s[255];
}

__global__ void scan2(int* __restrict__ bsum, int nb) {
  __shared__ int s[512];
  int t = threadIdx.x;
  int v = (t < nb) ? bsum[t] : 0;
  s[t] = v;
  __syncthreads();
  for (int off = 1; off < 512; off <<= 1) {
    int add = (t >= off) ? s[t - off] : 0;
    __syncthreads();
    s[t] += add;
    __syncthreads();
  }
  if (t < nb) bsum[t] = s[t] - v;
}

// ---------------- bucket scatter (global offsets = off + bsum) ----------------
__global__ __launch_bounds__(256) void bucket_scatter(const int* __restrict__ src,
                                                      const int* __restrict__ dst,
                                                      const int* __restrict__ off,
                                                      const int* __restrict__ bsum,
                                                      uint* __restrict__ pk) {
  __shared__ int cur[NPARTS];
  int t = threadIdx.x, c = blockIdx.x;
  for (int i = t; i < NPARTS; i += 256) {
    int idx = i * NCHUNKS + c;
    cur[i] = off[idx] + bsum[idx >> 8];
  }
  __syncthreads();
  int beg = c * CE;
  for (int j = t; j < CE; j += 256) {
    int d = dst[beg + j];
    int p = d / PW;
    int pos = atomicAdd(&cur[p], 1);
    pk[pos] = (uint)src[beg + j] | ((uint)(d - p * PW) << 17);
  }
}

// ---------------- csr_finalize: single pk read (register-cached, static indices) ----------------
__global__ __launch_bounds__(256) void csr_finalize(const uint* __restrict__ pk,
                                                    const int* __restrict__ off,
                                                    const int* __restrict__ bsum,
                                                    int* __restrict__ row_off,
                                                    float* __restrict__ dinv,
                                                    int* __restrict__ csr) {
  __shared__ int hist[PW];
  __shared__ int cur[PW];
  __shared__ int s[256];
  int p = blockIdx.x, t = threadIdx.x;
  int idx0 = p * NCHUNKS;
  int base = off[idx0] + bsum[idx0 >> 8];
  int endp = NE;
  if (p < NPARTS - 1) {
    int idx1 = (p + 1) * NCHUNKS;
    endp = off[idx1] + bsum[idx1 >> 8];
  }
  if (t < PW) hist[t] = 0;
  __syncthreads();
  uint my[16];
#pragma unroll
  for (int u = 0; u < 16; ++u) {
    int j = base + t + u * 256;
    uint e = 0xFFFFFFFFu;
    if (j < endp) e = pk[j];
    my[u] = e;
    if (e != 0xFFFFFFFFu) atomicAdd(&hist[e >> 17], 1);
  }
  // safety fallback for spans > 4096 (≈ +16 sigma; never in practice)
  for (int j = base + t + 16 * 256; j < endp; j += 256) atomicAdd(&hist[pk[j] >> 17], 1);
  __syncthreads();
  int v = (t < PW) ? hist[t] : 0;
  s[t] = v;
  __syncthreads();
  for (int o = 1; o < 256; o <<= 1) {
    int add = (t >= o) ? s[t - o] : 0;
    __syncthreads();
    s[t] += add;
    __syncthreads();
  }
  if (t < PW) {
    int excl = base + (s[t] - v);
    int node = p * PW + t;
    row_off[node] = excl;
    dinv[node]    = rsqrtf((float)v + 1.0f);
    cur[t] = excl;
  }
  if (p == NPARTS - 1 && t == 0) row_off[NN] = NE;
  __syncthreads();
#pragma unroll
  for (int u = 0; u < 16; ++u) {
    uint e = my[u];
    if (e != 0xFFFFFFFFu) {
      int pos = atomicAdd(&cur[e >> 17], 1);
      csr[pos] = (int)(e & 0x1FFFFu);
    }
  }
  for (int j = base + t + 16 * 256; j < endp; j += 256) {
    uint e = pk[j];
    int pos = atomicAdd(&cur[e >> 17], 1);
    csr[pos] = (int)(e & 0x1FFFFu);
  }
}

// ---------------- barrier-free skinny MFMA GEMM ----------------
template<int K, int N, int WM, int WN, int A_BF16, int RELU>
__global__ __launch_bounds__(256) void gemm_direct(const void* __restrict__ Av,
                                                   const uint* __restrict__ Bt,
                                                   const float* __restrict__ dinv,
                                                   ushort* __restrict__ Cb, int M) {
  constexpr int NW = N / WN;     // cols per wave
  constexpr int NT = NW / 16;    // b-frags per wave
  __shared__ __align__(16) char bsm[N * K * 2];
  const int tid  = threadIdx.x;
  const int wid  = tid >> 6;
  const int lane = tid & 63;
  const int wm   = wid % WM;
  const int wn   = wid / WM;
  const int l15  = lane & 15;
  const int lk   = lane >> 4;
  const int blockRow = blockIdx.x * (WM * 32);

  constexpr int UPR = K / 8;        // uint4 per B row
  constexpr int TOT = N * K / 8;    // total uint4
#pragma unroll
  for (int i0 = 0; i0 < TOT; i0 += 256) {
    int i = i0 + tid;
    uint4 v = reinterpret_cast<const uint4*>(Bt)[i];
    int n = i / UPR, c = i % UPR;
    int byte = (n * (K * 2) + c * 16) ^ ((n & 7) << 4);
    *reinterpret_cast<uint4*>(bsm + byte) = v;
  }
  __syncthreads();

  f32x4 acc[2][NT];
#pragma unroll
  for (int i = 0; i < 2; ++i)
#pragma unroll
    for (int j = 0; j < NT; ++j) acc[i][j] = (f32x4){0.f, 0.f, 0.f, 0.f};

#pragma unroll
  for (int kk = 0; kk < K / 32; ++kk) {
    bf16x8 af[2], bfr[NT];
#pragma unroll
    for (int mt = 0; mt < 2; ++mt) {
      int grow = blockRow + wm * 32 + mt * 16 + l15;
      int row = grow < M ? grow : M - 1;
      if (A_BF16) {
        uint4 va = *reinterpret_cast<const uint4*>((const uint*)Av + (size_t)row * (K / 2) + kk * 16 + lk * 4);
        if (RELU) { va.x = relu2(va.x); va.y = relu2(va.y); va.z = relu2(va.z); va.w = relu2(va.w); }
        af[mt] = __builtin_bit_cast(bf16x8, va);
      } else {
        const float4* p = reinterpret_cast<const float4*>((const float*)Av + (size_t)row * K + kk * 32 + lk * 8);
        float4 f0 = p[0], f1 = p[1];
        uint4 va;
        va.x = f2bf2(f0.x, f0.y); va.y = f2bf2(f0.z, f0.w);
        va.z = f2bf2(f1.x, f1.y); va.w = f2bf2(f1.z, f1.w);
        af[mt] = __builtin_bit_cast(bf16x8, va);
      }
    }
#pragma unroll
    for (int nt = 0; nt < NT; ++nt) {
      int n = wn * NW + nt * 16 + l15;
      int byte = (n * (K * 2) + kk * 64 + lk * 16) ^ ((n & 7) << 4);
      bfr[nt] = __builtin_bit_cast(bf16x8, *reinterpret_cast<uint4*>(bsm + byte));
    }
#pragma unroll
    for (int mt = 0; mt < 2; ++mt)
#pragma unroll
      for (int nt = 0; nt < NT; ++nt)
        acc[mt][nt] = __builtin_amdgcn_mfma_f32_16x16x32_bf16(af[mt], bfr[nt], acc[mt][nt], 0, 0, 0);
  }

#pragma unroll
  for (int mt = 0; mt < 2; ++mt) {
    int rbase = blockRow + wm * 32 + mt * 16 + lk * 4;
#pragma unroll
    for (int j = 0; j < 4; ++j) {
      int grow = rbase + j;
      if (grow < M) {
        float d = dinv[grow];
#pragma unroll
        for (int nt = 0; nt < NT; ++nt) {
          int gcol = wn * NW + nt * 16 + l15;
          Cb[(size_t)grow * N + gcol] = f2bf(acc[mt][nt][j] * d);
        }
      }
    }
  }
}

// ---------------- conv1 agg: wave per node, 4 edge slots x 16 lanes x uint4 ----------------
__global__ __launch_bounds__(256) void agg_csr_f128_v2(const uint4* __restrict__ hs,
                                                       const float* __restrict__ dinv,
                                                       const float* __restrict__ bias,
                                                       const int* __restrict__ row_off,
                                                       const int* __restrict__ csr,
                                                       uint4* __restrict__ outb, int N) {
  int node = blockIdx.x * 4 + (threadIdx.x >> 6);
  if (node >= N) return;
  int lane = threadIdx.x & 63;
  int sl = lane >> 4;      // edge slot 0..3
  int c4 = lane & 15;      // uint4 column within row
  int beg = row_off[node], end = row_off[node + 1];
  float a0=0,a1=0,a2=0,a3=0,a4=0,a5=0,a6=0,a7=0;
  int j = beg;
  for (; j + 16 <= end; j += 16) {
    int s0 = csr[j + sl];
    int s1 = csr[j + 4 + sl];
    int s2 = csr[j + 8 + sl];
    int s3 = csr[j + 12 + sl];
    uint4 v0 = hs[(size_t)s0 * 16 + c4];
    uint4 v1 = hs[(size_t)s1 * 16 + c4];
    uint4 v2 = hs[(size_t)s2 * 16 + c4];
    uint4 v3 = hs[(size_t)s3 * 16 + c4];
    float2 f;
    f = bf2f(v0.x); a0+=f.x; a1+=f.y;  f = bf2f(v0.y); a2+=f.x; a3+=f.y;
    f = bf2f(v0.z); a4+=f.x; a5+=f.y;  f = bf2f(v0.w); a6+=f.x; a7+=f.y;
    f = bf2f(v1.x); a0+=f.x; a1+=f.y;  f = bf2f(v1.y); a2+=f.x; a3+=f.y;
    f = bf2f(v1.z); a4+=f.x; a5+=f.y;  f = bf2f(v1.w); a6+=f.x; a7+=f.y;
    f = bf2f(v2.x); a0+=f.x; a1+=f.y;  f = bf2f(v2.y); a2+=f.x; a3+=f.y;
    f = bf2f(v2.z); a4+=f.x; a5+=f.y;  f = bf2f(v2.w); a6+=f.x; a7+=f.y;
    f = bf2f(v3.x); a0+=f.x; a1+=f.y;  f = bf2f(v3.y); a2+=f.x; a3+=f.y;
    f = bf2f(v3.z); a4+=f.x; a5+=f.y;  f = bf2f(v3.w); a6+=f.x; a7+=f.y;
  }
  for (; j + 4 <= end; j += 4) {
    int s0 = csr[j + sl];
    uint4 v0 = hs[(size_t)s0 * 16 + c4];
    float2 f;
    f = bf2f(v0.x); a0+=f.x; a1+=f.y;  f = bf2f(v0.y); a2+=f.x; a3+=f.y;
    f = bf2f(v0.z); a4+=f.x; a5+=f.y;  f = bf2f(v0.w); a6+=f.x; a7+=f.y;
  }
  if (j + sl < end) {
    int s0 = csr[j + sl];
    uint4 v0 = hs[(size_t)s0 * 16 + c4];
    float2 f;
    f = bf2f(v0.x); a0+=f.x; a1+=f.y;  f = bf2f(v0.y); a2+=f.x; a3+=f.y;
    f = bf2f(v0.z); a4+=f.x; a5+=f.y;  f = bf2f(v0.w); a6+=f.x; a7+=f.y;
  }
  a0 += __shfl_xor(a0, 16); a1 += __shfl_xor(a1, 16); a2 += __shfl_xor(a2, 16); a3 += __shfl_xor(a3, 16);
  a4 += __shfl_xor(a4, 16); a5 += __shfl_xor(a5, 16); a6 += __shfl_xor(a6, 16); a7 += __shfl_xor(a7, 16);
  a0 += __shfl_xor(a0, 32); a1 += __shfl_xor(a1, 32); a2 += __shfl_xor(a2, 32); a3 += __shfl_xor(a3, 32);
  a4 += __shfl_xor(a4, 32); a5 += __shfl_xor(a5, 32); a6 += __shfl_xor(a6, 32); a7 += __shfl_xor(a7, 32);
  if (sl == 0) {
    uint4 v = hs[(size_t)node * 16 + c4];  // self
    float2 f;
    f = bf2f(v.x); a0+=f.x; a1+=f.y;  f = bf2f(v.y); a2+=f.x; a3+=f.y;
    f = bf2f(v.z); a4+=f.x; a5+=f.y;  f = bf2f(v.w); a6+=f.x; a7+=f.y;
    float d = dinv[node];
    const float4* bp = reinterpret_cast<const float4*>(bias);
    float4 b0 = bp[c4 * 2], b1 = bp[c4 * 2 + 1];
    uint4 o;
    o.x = f2bf2(fmaf(a0, d, b0.x), fmaf(a1, d, b0.y));
    o.y = f2bf2(fmaf(a2, d, b0.z), fmaf(a3, d, b0.w));
    o.z = f2bf2(fmaf(a4, d, b1.x), fmaf(a5, d, b1.y));
    o.w = f2bf2(fmaf(a6, d, b1.z), fmaf(a7, d, b1.w));
    outb[(size_t)node * 16 + c4] = o;
  }
}

// ---------------- conv2 agg: wave per node, 8 edge slots x 8 lanes x uint4, bf16 out ----------------
// bias deferred to MLP
__global__ __launch_bounds__(256) void agg_csr_f64_v3(const uint4* __restrict__ hs,
                                                      const float* __restrict__ dinv,
                                                      const int* __restrict__ row_off,
                                                      const int* __restrict__ csr,
                                                      uint4* __restrict__ outb, int N) {
  int node = blockIdx.x * 4 + (threadIdx.x >> 6);
  if (node >= N) return;
  int lane = threadIdx.x & 63;
  int sl = lane >> 3;      // edge slot 0..7
  int c4 = lane & 7;       // uint4 column
  int beg = row_off[node], end = row_off[node + 1];
  float a0=0,a1=0,a2=0,a3=0,a4=0,a5=0,a6=0,a7=0;
  int j = beg;
  for (; j + 16 <= end; j += 16) {
    int s0 = csr[j + sl];
    int s1 = csr[j + 8 + sl];
    uint4 v0 = hs[(size_t)s0 * 8 + c4];
    uint4 v1 = hs[(size_t)s1 * 8 + c4];
    float2 f;
    f = bf2f(v0.x); a0+=f.x; a1+=f.y;  f = bf2f(v0.y); a2+=f.x; a3+=f.y;
    f = bf2f(v0.z); a4+=f.x; a5+=f.y;  f = bf2f(v0.w); a6+=f.x; a7+=f.y;
    f = bf2f(v1.x); a0+=f.x; a1+=f.y;  f = bf2f(v1.y); a2+=f.x; a3+=f.y;
    f = bf2f(v1.z); a4+=f.x; a5+=f.y;  f = bf2f(v1.w); a6+=f.x; a7+=f.y;
  }
  for (; j + 8 <= end; j += 8) {
    int s0 = csr[j + sl];
    uint4 v0 = hs[(size_t)s0 * 8 + c4];
    float2 f;
    f = bf2f(v0.x); a0+=f.x; a1+=f.y;  f = bf2f(v0.y); a2+=f.x; a3+=f.y;
    f = bf2f(v0.z); a4+=f.x; a5+=f.y;  f = bf2f(v0.w); a6+=f.x; a7+=f.y;
  }
  if (j + sl < end) {
    int s0 = csr[j + sl];
    uint4 v0 = hs[(size_t)s0 * 8 + c4];
    float2 f;
    f = bf2f(v0.x); a0+=f.x; a1+=f.y;  f = bf2f(v0.y); a2+=f.x; a3+=f.y;
    f = bf2f(v0.z); a4+=f.x; a5+=f.y;  f = bf2f(v0.w); a6+=f.x; a7+=f.y;
  }
  a0 += __shfl_xor(a0, 8);  a1 += __shfl_xor(a1, 8);  a2 += __shfl_xor(a2, 8);  a3 += __shfl_xor(a3, 8);
  a4 += __shfl_xor(a4, 8);  a5 += __shfl_xor(a5, 8);  a6 += __shfl_xor(a6, 8);  a7 += __shfl_xor(a7, 8);
  a0 += __shfl_xor(a0, 16); a1 += __shfl_xor(a1, 16); a2 += __shfl_xor(a2, 16); a3 += __shfl_xor(a3, 16);
  a4 += __shfl_xor(a4, 16); a5 += __shfl_xor(a5, 16); a6 += __shfl_xor(a6, 16); a7 += __shfl_xor(a7, 16);
  a0 += __shfl_xor(a0, 32); a1 += __shfl_xor(a1, 32); a2 += __shfl_xor(a2, 32); a3 += __shfl_xor(a3, 32);
  a4 += __shfl_xor(a4, 32); a5 += __shfl_xor(a5, 32); a6 += __shfl_xor(a6, 32); a7 += __shfl_xor(a7, 32);
  if (sl == 0) {
    uint4 v = hs[(size_t)node * 8 + c4];  // self
    float2 f;
    f = bf2f(v.x); a0+=f.x; a1+=f.y;  f = bf2f(v.y); a2+=f.x; a3+=f.y;
    f = bf2f(v.z); a4+=f.x; a5+=f.y;  f = bf2f(v.w); a6+=f.x; a7+=f.y;
    float d = dinv[node];
    uint4 o;
    o.x = f2bf2(a0 * d, a1 * d);
    o.y = f2bf2(a2 * d, a3 * d);
    o.z = f2bf2(a4 * d, a5 * d);
    o.w = f2bf2(a6 * d, a7 * d);
    outb[(size_t)node * 8 + c4] = o;
  }
}

// ---------------- fused per-graph mean pool (bf16 in) + MLP (adds deferred b2) ----------------
__global__ __launch_bounds__(256) void pool_mlp(const uint* __restrict__ hb,
                                                const int* __restrict__ batch,
                                                const float* __restrict__ scalars,
                                                const float* __restrict__ b2,
                                                const float* __restrict__ W3,
                                                const float* __restrict__ b3,
                                                const float* __restrict__ W4,
                                                const float* __restrict__ b4,
                                                float* __restrict__ out, int N) {
  int g = blockIdx.x;
  int t = threadIdx.x;  // 256
  int c = t & 31, rr = t >> 5;   // 8 row-groups x 32 packed cols
  __shared__ int range[2];
  __shared__ float2 part[8][32];
  __shared__ float comb[66];
  __shared__ float red[2];
  if (t < 2) {
    int target = g + t;
    int lo = 0, hi = N;
    while (lo < hi) { int mid = (lo + hi) >> 1; if (batch[mid] < target) lo = mid + 1; else hi = mid; }
    range[t] = lo;
  }
  __syncthreads();
  int beg = range[0], end = range[1];
  float sx = 0.f, sy = 0.f;
  for (int i = beg + rr; i < end; i += 8) {
    float2 f = bf2f(hb[(size_t)i * 32 + c]);
    sx += f.x; sy += f.y;
  }
  part[rr][c] = make_float2(sx, sy);
  __syncthreads();
  if (rr == 0) {
    float tx = 0.f, ty = 0.f;
#pragma unroll
    for (int r = 0; r < 8; ++r) { tx += part[r][c].x; ty += part[r][c].y; }
    float cnt = fmaxf((float)(end - beg), 1.f);
    comb[2 * c]     = tx / cnt + b2[2 * c];
    comb[2 * c + 1] = ty / cnt + b2[2 * c + 1];
  } else if (t == 64 || t == 65) {
    comb[t] = scalars[g * 2 + (t - 64)];
  }
  __syncthreads();
  if (t < 128) {
    float hh = b3[t];
#pragma unroll
    for (int k = 0; k < 66; ++k) hh += comb[k] * W3[k * 128 + t];
    hh = fmaxf(hh, 0.f);
    float p = hh * W4[t];
#pragma unroll
    for (int off = 32; off > 0; off >>= 1) p += __shfl_down(p, off);
    if ((t & 63) == 0) red[t >> 6] = p;
  }
  __syncthreads();
  if (t == 0) {
    float sum = red[0] + red[1] + b4[0];
    out[g] = 1.f / (1.f + expf(-sum));
  }
}

extern "C" void kernel_launch(void* const* d_in, const int* in_sizes, int n_in,
                              void* d_out, int out_size, void* d_ws, size_t ws_size,
                              hipStream_t stream) {
  const float* x       = (const float*)d_in[0];
  const int*   ei      = (const int*)d_in[1];
  const int*   src     = ei;
  const int*   dstp    = ei + NE;
  const int*   batch   = (const int*)d_in[2];
  const float* scalars = (const float*)d_in[3];
  const float* W1 = (const float*)d_in[4];  const float* b1 = (const float*)d_in[5];
  const float* W2 = (const float*)d_in[6];  const float* b2 = (const float*)d_in[7];
  const float* W3 = (const float*)d_in[8];  const float* b3 = (const float*)d_in[9];
  const float* W4 = (const float*)d_in[10]; const float* b4 = (const float*)d_in[11];
  float* out = (float*)d_out;

  // workspace layout (32-bit words) — 16B-aligned segments first
  uint*  ws      = (uint*)d_ws;
  uint*  w1t     = ws;                      // [128*128]  (W1^T bf16)
  uint*  w2t     = ws + 16384;              // [64*64]    (W2^T bf16)
  uint*  hsb     = ws + 20480;              // [100000,64]u bf16 hs; reused [100000,32]u
  uint*  agg1b   = hsb + 6400000;           // [100000,64]u bf16 agg1; reused agg2 bf16 [100000,32]u
  float* dinv    = (float*)(agg1b + 6400000); // [100000]
  int*   row_off = (int*)(dinv + NN);       // [100004] (padded)
  int*   csr     = row_off + NN + 4;        // [1600000]
  uint*  pk      = (uint*)(csr + NE);       // [1600000]
  int*   cnt     = (int*)(pk + NE);         // [64000]
  int*   bsum    = cnt + NCNT;              // [512]

  // prep: weight transposes + bucket counts (independent, one launch)
  prep<<<320, 256, 0, stream>>>(W1, w1t, W2, w2t, dstp, cnt);

  // CSR build (no global atomics); scan3 folded into consumers
  scan1<<<(NCNT + 255) / 256, 256, 0, stream>>>(cnt, cnt, bsum, NCNT);
  scan2<<<1, 512, 0, stream>>>(bsum, (NCNT + 255) / 256);
  bucket_scatter<<<NCHUNKS, 256, 0, stream>>>(src, dstp, cnt, bsum, pk);
  csr_finalize<<<NPARTS, 256, 0, stream>>>(pk, cnt, bsum, row_off, dinv, csr);

  // conv1: hsb = bf16((x @ W1) * dinv) ; agg1b = bf16(dinv*(gather+self) + b1)
  gemm_direct<256, 128, 4, 1, 0, 0><<<(NN + 127) / 128, 256, 0, stream>>>(
      x, w1t, dinv, (ushort*)hsb, NN);
  agg_csr_f128_v2<<<(NN + 3) / 4, 256, 0, stream>>>((const uint4*)hsb, dinv, b1,
                                                    row_off, csr, (uint4*)agg1b, NN);

  // conv2: hsb = bf16((relu(agg1b) @ W2) * dinv) ; agg2 = bf16(dinv*(gather+self)) (b2 deferred)
  gemm_direct<128, 64, 4, 1, 1, 1><<<(NN + 127) / 128, 256, 0, stream>>>(
      agg1b, w2t, dinv, (ushort*)hsb, NN);
  agg_csr_f64_v3<<<(NN + 3) / 4, 256, 0, stream>>>((const uint4*)hsb, dinv,
                                                   row_off, csr, (uint4*)agg1b, NN);

  // fused pool + MLP (b2 added here)
  pool_mlp<<<NG, 256, 0, stream>>>(agg1b, batch, scalars, b2,
                                   W3, b3, W4, b4, out, NN);
}

// Round 12
// 211.409 us; speedup vs baseline: 2.3735x; 1.0770x over previous
//
#include <hip/hip_runtime.h>

#define NN 100000
#define NE 1600000
#define NG 512
#define NPARTS 500    // dst partitions
#define PW 200        // partition width (500*200 = 100000)
#define NCHUNKS 256   // edge chunks
#define CE 6250       // edges per chunk (256*6250 = 1.6M)
#define NCNT (NPARTS * NCHUNKS)

typedef unsigned int uint;
typedef unsigned short ushort;
typedef __bf16 bf16x8 __attribute__((ext_vector_type(8)));
typedef float f32x4 __attribute__((ext_vector_type(4)));

// ---- bf16 pack helpers (round-to-nearest-even) ----
__device__ inline uint f2bf2(float a, float b) {
  uint ua = __float_as_uint(a), ub = __float_as_uint(b);
  ua += 0x7fff + ((ua >> 16) & 1);
  ub += 0x7fff + ((ub >> 16) & 1);
  return (ua >> 16) | (ub & 0xffff0000u);
}
__device__ inline ushort f2bf(float f) {
  uint u = __float_as_uint(f);
  u += 0x7fff + ((u >> 16) & 1);
  return (ushort)(u >> 16);
}
__device__ inline float2 bf2f(uint v) {
  float2 r;
  r.x = __uint_as_float(v << 16);
  r.y = __uint_as_float(v & 0xffff0000u);
  return r;
}
__device__ inline uint relu2(uint u) {
  uint lo = (u & 0x8000u) ? 0u : (u & 0xFFFFu);
  uint hi = (u & 0x80000000u) ? 0u : (u & 0xFFFF0000u);
  return lo | hi;
}

// ---------------- prep: weight transposes (blocks 0..191) + bucket_count (192..447) ----------------
__global__ __launch_bounds__(256) void prep(const float* __restrict__ W1, uint* __restrict__ w1t,
                                            const float* __restrict__ W2, uint* __restrict__ w2t,
                                            const int* __restrict__ dst, int* __restrict__ cnt) {
  int b = blockIdx.x, t = threadIdx.x;
  if (b < 192) {
    __shared__ float col[256];
    const float* W; uint* Wt; int K, N, n;
    if (b < 128) { W = W1; Wt = w1t; K = 256; N = 128; n = b; }
    else         { W = W2; Wt = w2t; K = 128; N = 64;  n = b - 128; }
    if (t < K) col[t] = W[(size_t)t * N + n];
    __syncthreads();
    if (t < K / 2) Wt[(size_t)n * (K / 2) + t] = f2bf2(col[2 * t], col[2 * t + 1]);
  } else {
    __shared__ int h[NPARTS];
    int c = b - 192;
    for (int i = t; i < NPARTS; i += 256) h[i] = 0;
    __syncthreads();
    int beg = c * CE;
    for (int j = t; j < CE; j += 256) atomicAdd(&h[dst[beg + j] / PW], 1);
    __syncthreads();
    for (int i = t; i < NPARTS; i += 256) cnt[i * NCHUNKS + c] = h[i];
  }
}

// ---------------- scan (block-local exclusive; bsum added at consumer) ----------------
__global__ void scan1(const int* __restrict__ in, int* __restrict__ out,
                      int* __restrict__ bsum, int n) {
  __shared__ int s[256];
  int t = threadIdx.x;
  int i = blockIdx.x * 256 + t;
  int v = (i < n) ? in[i] : 0;
  s[t] = v;
  __syncthreads();
  for (int off = 1; off < 256; off <<= 1) {
    int add = (t >= off) ? s[t - off] : 0;
    __syncthreads();
    s[t] += add;
    __syncthreads();
  }
  if (i < n) out[i] = s[t] - v;
  if (t == 255) bsum[blockIdx.x] = s[255];
}

__global__ void scan2(int* __restrict__ bsum, int nb) {
  __shared__ int s[512];
  int t = threadIdx.x;
  int v = (t < nb) ? bsum[t] : 0;
  s[t] = v;
  __syncthreads();
  for (int off = 1; off < 512; off <<= 1) {
    int add = (t >= off) ? s[t - off] : 0;
    __syncthreads();
    s[t] += add;
    __syncthreads();
  }
  if (t < nb) bsum[t] = s[t] - v;
}

// ---------------- bucket scatter (global offsets = off + bsum; bsum idx = partition) ----------------
__global__ __launch_bounds__(256) void bucket_scatter(const int* __restrict__ src,
                                                      const int* __restrict__ dst,
                                                      const int* __restrict__ off,
                                                      const int* __restrict__ bsum,
                                                      uint* __restrict__ pk) {
  __shared__ int cur[NPARTS];
  int t = threadIdx.x, c = blockIdx.x;
  for (int i = t; i < NPARTS; i += 256) {
    int idx = i * NCHUNKS + c;
    cur[i] = off[idx] + bsum[idx >> 8];   // NCHUNKS==256 -> idx>>8 == i
  }
  __syncthreads();
  int beg = c * CE;
  for (int j = t; j < CE; j += 256) {
    int d = dst[beg + j];
    int p = d / PW;
    int pos = atomicAdd(&cur[p], 1);
    pk[pos] = (uint)src[beg + j] | ((uint)(d - p * PW) << 17);
  }
}

// ---------------- csr_finalize: single pk read (register-cached, static indices) ----------------
__global__ __launch_bounds__(256) void csr_finalize(const uint* __restrict__ pk,
                                                    const int* __restrict__ off,
                                                    const int* __restrict__ bsum,
                                                    int* __restrict__ row_off,
                                                    float* __restrict__ dinv,
                                                    int* __restrict__ csr) {
  __shared__ int hist[PW];
  __shared__ int cur[PW];
  __shared__ int s[256];
  int p = blockIdx.x, t = threadIdx.x;
  int idx0 = p * NCHUNKS;
  int base = off[idx0] + bsum[idx0 >> 8];
  int endp = NE;
  if (p < NPARTS - 1) {
    int idx1 = (p + 1) * NCHUNKS;
    endp = off[idx1] + bsum[idx1 >> 8];
  }
  if (t < PW) hist[t] = 0;
  __syncthreads();
  uint my[16];
#pragma unroll
  for (int u = 0; u < 16; ++u) {
    int j = base + t + u * 256;
    uint e = 0xFFFFFFFFu;
    if (j < endp) e = pk[j];
    my[u] = e;
    if (e != 0xFFFFFFFFu) atomicAdd(&hist[e >> 17], 1);
  }
  // safety fallback for spans > 4096 (never in practice)
  for (int j = base + t + 16 * 256; j < endp; j += 256) atomicAdd(&hist[pk[j] >> 17], 1);
  __syncthreads();
  int v = (t < PW) ? hist[t] : 0;
  s[t] = v;
  __syncthreads();
  for (int o = 1; o < 256; o <<= 1) {
    int add = (t >= o) ? s[t - o] : 0;
    __syncthreads();
    s[t] += add;
    __syncthreads();
  }
  if (t < PW) {
    int excl = base + (s[t] - v);
    int node = p * PW + t;
    row_off[node] = excl;
    dinv[node]    = rsqrtf((float)v + 1.0f);
    cur[t] = excl;
  }
  if (p == NPARTS - 1 && t == 0) row_off[NN] = NE;
  __syncthreads();
#pragma unroll
  for (int u = 0; u < 16; ++u) {
    uint e = my[u];
    if (e != 0xFFFFFFFFu) {
      int pos = atomicAdd(&cur[e >> 17], 1);
      csr[pos] = (int)(e & 0x1FFFFu);
    }
  }
  for (int j = base + t + 16 * 256; j < endp; j += 256) {
    uint e = pk[j];
    int pos = atomicAdd(&cur[e >> 17], 1);
    csr[pos] = (int)(e & 0x1FFFFu);
  }
}

// ---------------- barrier-free skinny MFMA GEMM ----------------
template<int K, int N, int WM, int WN, int A_BF16, int RELU>
__global__ __launch_bounds__(256) void gemm_direct(const void* __restrict__ Av,
                                                   const uint* __restrict__ Bt,
                                                   const float* __restrict__ dinv,
                                                   ushort* __restrict__ Cb, int M) {
  constexpr int NW = N / WN;     // cols per wave
  constexpr int NT = NW / 16;    // b-frags per wave
  __shared__ __align__(16) char bsm[N * K * 2];
  const int tid  = threadIdx.x;
  const int wid  = tid >> 6;
  const int lane = tid & 63;
  const int wm   = wid % WM;
  const int wn   = wid / WM;
  const int l15  = lane & 15;
  const int lk   = lane >> 4;
  const int blockRow = blockIdx.x * (WM * 32);

  constexpr int UPR = K / 8;        // uint4 per B row
  constexpr int TOT = N * K / 8;    // total uint4
#pragma unroll
  for (int i0 = 0; i0 < TOT; i0 += 256) {
    int i = i0 + tid;
    uint4 v = reinterpret_cast<const uint4*>(Bt)[i];
    int n = i / UPR, c = i % UPR;
    int byte = (n * (K * 2) + c * 16) ^ ((n & 7) << 4);
    *reinterpret_cast<uint4*>(bsm + byte) = v;
  }
  __syncthreads();

  f32x4 acc[2][NT];
#pragma unroll
  for (int i = 0; i < 2; ++i)
#pragma unroll
    for (int j = 0; j < NT; ++j) acc[i][j] = (f32x4){0.f, 0.f, 0.f, 0.f};

#pragma unroll
  for (int kk = 0; kk < K / 32; ++kk) {
    bf16x8 af[2], bfr[NT];
#pragma unroll
    for (int mt = 0; mt < 2; ++mt) {
      int grow = blockRow + wm * 32 + mt * 16 + l15;
      int row = grow < M ? grow : M - 1;
      if (A_BF16) {
        uint4 va = *reinterpret_cast<const uint4*>((const uint*)Av + (size_t)row * (K / 2) + kk * 16 + lk * 4);
        if (RELU) { va.x = relu2(va.x); va.y = relu2(va.y); va.z = relu2(va.z); va.w = relu2(va.w); }
        af[mt] = __builtin_bit_cast(bf16x8, va);
      } else {
        const float4* p = reinterpret_cast<const float4*>((const float*)Av + (size_t)row * K + kk * 32 + lk * 8);
        float4 f0 = p[0], f1 = p[1];
        uint4 va;
        va.x = f2bf2(f0.x, f0.y); va.y = f2bf2(f0.z, f0.w);
        va.z = f2bf2(f1.x, f1.y); va.w = f2bf2(f1.z, f1.w);
        af[mt] = __builtin_bit_cast(bf16x8, va);
      }
    }
#pragma unroll
    for (int nt = 0; nt < NT; ++nt) {
      int n = wn * NW + nt * 16 + l15;
      int byte = (n * (K * 2) + kk * 64 + lk * 16) ^ ((n & 7) << 4);
      bfr[nt] = __builtin_bit_cast(bf16x8, *reinterpret_cast<uint4*>(bsm + byte));
    }
#pragma unroll
    for (int mt = 0; mt < 2; ++mt)
#pragma unroll
      for (int nt = 0; nt < NT; ++nt)
        acc[mt][nt] = __builtin_amdgcn_mfma_f32_16x16x32_bf16(af[mt], bfr[nt], acc[mt][nt], 0, 0, 0);
  }

#pragma unroll
  for (int mt = 0; mt < 2; ++mt) {
    int rbase = blockRow + wm * 32 + mt * 16 + lk * 4;
#pragma unroll
    for (int j = 0; j < 4; ++j) {
      int grow = rbase + j;
      if (grow < M) {
        float d = dinv[grow];
#pragma unroll
        for (int nt = 0; nt < NT; ++nt) {
          int gcol = wn * NW + nt * 16 + l15;
          Cb[(size_t)grow * N + gcol] = f2bf(acc[mt][nt][j] * d);
        }
      }
    }
  }
}

// ---------------- conv1 agg: wave per node, 4 edge slots x 16 lanes x uint4 ----------------
__global__ __launch_bounds__(256) void agg_csr_f128_v2(const uint4* __restrict__ hs,
                                                       const float* __restrict__ dinv,
                                                       const float* __restrict__ bias,
                                                       const int* __restrict__ row_off,
                                                       const int* __restrict__ csr,
                                                       uint4* __restrict__ outb, int N) {
  int node = blockIdx.x * 4 + (threadIdx.x >> 6);
  if (node >= N) return;
  int lane = threadIdx.x & 63;
  int sl = lane >> 4;      // edge slot 0..3
  int c4 = lane & 15;      // uint4 column within row
  int beg = row_off[node], end = row_off[node + 1];
  float a0=0,a1=0,a2=0,a3=0,a4=0,a5=0,a6=0,a7=0;
  int j = beg;
  for (; j + 16 <= end; j += 16) {
    int s0 = csr[j + sl];
    int s1 = csr[j + 4 + sl];
    int s2 = csr[j + 8 + sl];
    int s3 = csr[j + 12 + sl];
    uint4 v0 = hs[(size_t)s0 * 16 + c4];
    uint4 v1 = hs[(size_t)s1 * 16 + c4];
    uint4 v2 = hs[(size_t)s2 * 16 + c4];
    uint4 v3 = hs[(size_t)s3 * 16 + c4];
    float2 f;
    f = bf2f(v0.x); a0+=f.x; a1+=f.y;  f = bf2f(v0.y); a2+=f.x; a3+=f.y;
    f = bf2f(v0.z); a4+=f.x; a5+=f.y;  f = bf2f(v0.w); a6+=f.x; a7+=f.y;
    f = bf2f(v1.x); a0+=f.x; a1+=f.y;  f = bf2f(v1.y); a2+=f.x; a3+=f.y;
    f = bf2f(v1.z); a4+=f.x; a5+=f.y;  f = bf2f(v1.w); a6+=f.x; a7+=f.y;
    f = bf2f(v2.x); a0+=f.x; a1+=f.y;  f = bf2f(v2.y); a2+=f.x; a3+=f.y;
    f = bf2f(v2.z); a4+=f.x; a5+=f.y;  f = bf2f(v2.w); a6+=f.x; a7+=f.y;
    f = bf2f(v3.x); a0+=f.x; a1+=f.y;  f = bf2f(v3.y); a2+=f.x; a3+=f.y;
    f = bf2f(v3.z); a4+=f.x; a5+=f.y;  f = bf2f(v3.w); a6+=f.x; a7+=f.y;
  }
  for (; j + 4 <= end; j += 4) {
    int s0 = csr[j + sl];
    uint4 v0 = hs[(size_t)s0 * 16 + c4];
    float2 f;
    f = bf2f(v0.x); a0+=f.x; a1+=f.y;  f = bf2f(v0.y); a2+=f.x; a3+=f.y;
    f = bf2f(v0.z); a4+=f.x; a5+=f.y;  f = bf2f(v0.w); a6+=f.x; a7+=f.y;
  }
  if (j + sl < end) {
    int s0 = csr[j + sl];
    uint4 v0 = hs[(size_t)s0 * 16 + c4];
    float2 f;
    f = bf2f(v0.x); a0+=f.x; a1+=f.y;  f = bf2f(v0.y); a2+=f.x; a3+=f.y;
    f = bf2f(v0.z); a4+=f.x; a5+=f.y;  f = bf2f(v0.w); a6+=f.x; a7+=f.y;
  }
  a0 += __shfl_xor(a0, 16); a1 += __shfl_xor(a1, 16); a2 += __shfl_xor(a2, 16); a3 += __shfl_xor(a3, 16);
  a4 += __shfl_xor(a4, 16); a5 += __shfl_xor(a5, 16); a6 += __shfl_xor(a6, 16); a7 += __shfl_xor(a7, 16);
  a0 += __shfl_xor(a0, 32); a1 += __shfl_xor(a1, 32); a2 += __shfl_xor(a2, 32); a3 += __shfl_xor(a3, 32);
  a4 += __shfl_xor(a4, 32); a5 += __shfl_xor(a5, 32); a6 += __shfl_xor(a6, 32); a7 += __shfl_xor(a7, 32);
  if (sl == 0) {
    uint4 v = hs[(size_t)node * 16 + c4];  // self
    float2 f;
    f = bf2f(v.x); a0+=f.x; a1+=f.y;  f = bf2f(v.y); a2+=f.x; a3+=f.y;
    f = bf2f(v.z); a4+=f.x; a5+=f.y;  f = bf2f(v.w); a6+=f.x; a7+=f.y;
    float d = dinv[node];
    const float4* bp = reinterpret_cast<const float4*>(bias);
    float4 b0 = bp[c4 * 2], b1 = bp[c4 * 2 + 1];
    uint4 o;
    o.x = f2bf2(fmaf(a0, d, b0.x), fmaf(a1, d, b0.y));
    o.y = f2bf2(fmaf(a2, d, b0.z), fmaf(a3, d, b0.w));
    o.z = f2bf2(fmaf(a4, d, b1.x), fmaf(a5, d, b1.y));
    o.w = f2bf2(fmaf(a6, d, b1.z), fmaf(a7, d, b1.w));
    outb[(size_t)node * 16 + c4] = o;
  }
}

// ---------------- conv2 agg: wave per node, 8 edge slots x 8 lanes x uint4, bf16 out ----------------
__global__ __launch_bounds__(256) void agg_csr_f64_v3(const uint4* __restrict__ hs,
                                                      const float* __restrict__ dinv,
                                                      const int* __restrict__ row_off,
                                                      const int* __restrict__ csr,
                                                      uint4* __restrict__ outb, int N) {
  int node = blockIdx.x * 4 + (threadIdx.x >> 6);
  if (node >= N) return;
  int lane = threadIdx.x & 63;
  int sl = lane >> 3;      // edge slot 0..7
  int c4 = lane & 7;       // uint4 column
  int beg = row_off[node], end = row_off[node + 1];
  float a0=0,a1=0,a2=0,a3=0,a4=0,a5=0,a6=0,a7=0;
  int j = beg;
  for (; j + 16 <= end; j += 16) {
    int s0 = csr[j + sl];
    int s1 = csr[j + 8 + sl];
    uint4 v0 = hs[(size_t)s0 * 8 + c4];
    uint4 v1 = hs[(size_t)s1 * 8 + c4];
    float2 f;
    f = bf2f(v0.x); a0+=f.x; a1+=f.y;  f = bf2f(v0.y); a2+=f.x; a3+=f.y;
    f = bf2f(v0.z); a4+=f.x; a5+=f.y;  f = bf2f(v0.w); a6+=f.x; a7+=f.y;
    f = bf2f(v1.x); a0+=f.x; a1+=f.y;  f = bf2f(v1.y); a2+=f.x; a3+=f.y;
    f = bf2f(v1.z); a4+=f.x; a5+=f.y;  f = bf2f(v1.w); a6+=f.x; a7+=f.y;
  }
  for (; j + 8 <= end; j += 8) {
    int s0 = csr[j + sl];
    uint4 v0 = hs[(size_t)s0 * 8 + c4];
    float2 f;
    f = bf2f(v0.x); a0+=f.x; a1+=f.y;  f = bf2f(v0.y); a2+=f.x; a3+=f.y;
    f = bf2f(v0.z); a4+=f.x; a5+=f.y;  f = bf2f(v0.w); a6+=f.x; a7+=f.y;
  }
  if (j + sl < end) {
    int s0 = csr[j + sl];
    uint4 v0 = hs[(size_t)s0 * 8 + c4];
    float2 f;
    f = bf2f(v0.x); a0+=f.x; a1+=f.y;  f = bf2f(v0.y); a2+=f.x; a3+=f.y;
    f = bf2f(v0.z); a4+=f.x; a5+=f.y;  f = bf2f(v0.w); a6+=f.x; a7+=f.y;
  }
  a0 += __shfl_xor(a0, 8);  a1 += __shfl_xor(a1, 8);  a2 += __shfl_xor(a2, 8);  a3 += __shfl_xor(a3, 8);
  a4 += __shfl_xor(a4, 8);  a5 += __shfl_xor(a5, 8);  a6 += __shfl_xor(a6, 8);  a7 += __shfl_xor(a7, 8);
  a0 += __shfl_xor(a0, 16); a1 += __shfl_xor(a1, 16); a2 += __shfl_xor(a2, 16); a3 += __shfl_xor(a3, 16);
  a4 += __shfl_xor(a4, 16); a5 += __shfl_xor(a5, 16); a6 += __shfl_xor(a6, 16); a7 += __shfl_xor(a7, 16);
  a0 += __shfl_xor(a0, 32); a1 += __shfl_xor(a1, 32); a2 += __shfl_xor(a2, 32); a3 += __shfl_xor(a3, 32);
  a4 += __shfl_xor(a4, 32); a5 += __shfl_xor(a5, 32); a6 += __shfl_xor(a6, 32); a7 += __shfl_xor(a7, 32);
  if (sl == 0) {
    uint4 v = hs[(size_t)node * 8 + c4];  // self
    float2 f;
    f = bf2f(v.x); a0+=f.x; a1+=f.y;  f = bf2f(v.y); a2+=f.x; a3+=f.y;
    f = bf2f(v.z); a4+=f.x; a5+=f.y;  f = bf2f(v.w); a6+=f.x; a7+=f.y;
    float d = dinv[node];
    uint4 o;
    o.x = f2bf2(a0 * d, a1 * d);
    o.y = f2bf2(a2 * d, a3 * d);
    o.z = f2bf2(a4 * d, a5 * d);
    o.w = f2bf2(a6 * d, a7 * d);
    outb[(size_t)node * 8 + c4] = o;
  }
}

// ---------------- fused per-graph mean pool (bf16 in) + MLP (adds deferred b2) ----------------
__global__ __launch_bounds__(256) void pool_mlp(const uint* __restrict__ hb,
                                                const int* __restrict__ batch,
                                                const float* __restrict__ scalars,
                                                const float* __restrict__ b2,
                                                const float* __restrict__ W3,
                                                const float* __restrict__ b3,
                                                const float* __restrict__ W4,
                                                const float* __restrict__ b4,
                                                float* __restrict__ out, int N) {
  int g = blockIdx.x;
  int t = threadIdx.x;  // 256
  int c = t & 31, rr = t >> 5;   // 8 row-groups x 32 packed cols
  __shared__ int range[2];
  __shared__ float2 part[8][32];
  __shared__ float comb[66];
  __shared__ float red[2];
  if (t < 2) {
    int target = g + t;
    int lo = 0, hi = N;
    while (lo < hi) { int mid = (lo + hi) >> 1; if (batch[mid] < target) lo = mid + 1; else hi = mid; }
    range[t] = lo;
  }
  __syncthreads();
  int beg = range[0], end = range[1];
  float sx = 0.f, sy = 0.f;
  for (int i = beg + rr; i < end; i += 8) {
    float2 f = bf2f(hb[(size_t)i * 32 + c]);
    sx += f.x; sy += f.y;
  }
  part[rr][c] = make_float2(sx, sy);
  __syncthreads();
  if (rr == 0) {
    float tx = 0.f, ty = 0.f;
#pragma unroll
    for (int r = 0; r < 8; ++r) { tx += part[r][c].x; ty += part[r][c].y; }
    float cnt = fmaxf((float)(end - beg), 1.f);
    comb[2 * c]     = tx / cnt + b2[2 * c];
    comb[2 * c + 1] = ty / cnt + b2[2 * c + 1];
  } else if (t == 64 || t == 65) {
    comb[t] = scalars[g * 2 + (t - 64)];
  }
  __syncthreads();
  if (t < 128) {
    float hh = b3[t];
#pragma unroll
    for (int k = 0; k < 66; ++k) hh += comb[k] * W3[k * 128 + t];
    hh = fmaxf(hh, 0.f);
    float p = hh * W4[t];
#pragma unroll
    for (int off = 32; off > 0; off >>= 1) p += __shfl_down(p, off);
    if ((t & 63) == 0) red[t >> 6] = p;
  }
  __syncthreads();
  if (t == 0) {
    float sum = red[0] + red[1] + b4[0];
    out[g] = 1.f / (1.f + expf(-sum));
  }
}

extern "C" void kernel_launch(void* const* d_in, const int* in_sizes, int n_in,
                              void* d_out, int out_size, void* d_ws, size_t ws_size,
                              hipStream_t stream) {
  const float* x       = (const float*)d_in[0];
  const int*   ei      = (const int*)d_in[1];
  const int*   src     = ei;
  const int*   dstp    = ei + NE;
  const int*   batch   = (const int*)d_in[2];
  const float* scalars = (const float*)d_in[3];
  const float* W1 = (const float*)d_in[4];  const float* b1 = (const float*)d_in[5];
  const float* W2 = (const float*)d_in[6];  const float* b2 = (const float*)d_in[7];
  const float* W3 = (const float*)d_in[8];  const float* b3 = (const float*)d_in[9];
  const float* W4 = (const float*)d_in[10]; const float* b4 = (const float*)d_in[11];
  float* out = (float*)d_out;

  // workspace layout (32-bit words) — 16B-aligned segments first
  uint*  ws      = (uint*)d_ws;
  uint*  w1t     = ws;                      // [128*128]  (W1^T bf16)
  uint*  w2t     = ws + 16384;              // [64*64]    (W2^T bf16)
  uint*  hsb     = ws + 20480;              // [100000,64]u bf16 hs; reused [100000,32]u
  uint*  agg1b   = hsb + 6400000;           // [100000,64]u bf16 agg1; reused agg2 bf16 [100000,32]u
  float* dinv    = (float*)(agg1b + 6400000); // [100000]
  int*   row_off = (int*)(dinv + NN);       // [100004] (padded)
  int*   csr     = row_off + NN + 4;        // [1600000]
  uint*  pk      = (uint*)(csr + NE);       // [1600000]
  int*   cnt     = (int*)(pk + NE);         // [128000]
  int*   bsum    = cnt + NCNT;              // [512]

  // prep: weight transposes + bucket counts (independent, one launch)
  prep<<<448, 256, 0, stream>>>(W1, w1t, W2, w2t, dstp, cnt);

  // CSR build (no global atomics)
  scan1<<<(NCNT + 255) / 256, 256, 0, stream>>>(cnt, cnt, bsum, NCNT);
  scan2<<<1, 512, 0, stream>>>(bsum, (NCNT + 255) / 256);
  bucket_scatter<<<NCHUNKS, 256, 0, stream>>>(src, dstp, cnt, bsum, pk);
  csr_finalize<<<NPARTS, 256, 0, stream>>>(pk, cnt, bsum, row_off, dinv, csr);

  // conv1: hsb = bf16((x @ W1) * dinv) ; agg1b = bf16(dinv*(gather+self) + b1)
  gemm_direct<256, 128, 4, 1, 0, 0><<<(NN + 127) / 128, 256, 0, stream>>>(
      x, w1t, dinv, (ushort*)hsb, NN);
  agg_csr_f128_v2<<<(NN + 3) / 4, 256, 0, stream>>>((const uint4*)hsb, dinv, b1,
                                                    row_off, csr, (uint4*)agg1b, NN);

  // conv2: hsb = bf16((relu(agg1b) @ W2) * dinv) ; agg2 = bf16(dinv*(gather+self)) (b2 deferred)
  gemm_direct<128, 64, 4, 1, 1, 1><<<(NN + 127) / 128, 256, 0, stream>>>(
      agg1b, w2t, dinv, (ushort*)hsb, NN);
  agg_csr_f64_v3<<<(NN + 3) / 4, 256, 0, stream>>>((const uint4*)hsb, dinv,
                                                   row_off, csr, (uint4*)agg1b, NN);

  // fused pool + MLP (b2 added here)
  pool_mlp<<<NG, 256, 0, stream>>>(agg1b, batch, scalars, b2,
                                   W3, b3, W4, b4, out, NN);
}

// Round 13
// 207.007 us; speedup vs baseline: 2.4240x; 1.0213x over previous
//
#include <hip/hip_runtime.h>

#define NN 100000
#define NE 1600000
#define NG 512
#define NPARTS 500    // dst partitions
#define PW 200        // partition width (500*200 = 100000)
#define NCHUNKS 512   // edge chunks
#define CE 3125       // edges per chunk (512*3125 = 1.6M)
#define NCNT (NPARTS * NCHUNKS)

typedef unsigned int uint;
typedef unsigned short ushort;
typedef __bf16 bf16x8 __attribute__((ext_vector_type(8)));
typedef float f32x4 __attribute__((ext_vector_type(4)));

// ---- bf16 pack helpers (round-to-nearest-even) ----
__device__ inline uint f2bf2(float a, float b) {
  uint ua = __float_as_uint(a), ub = __float_as_uint(b);
  ua += 0x7fff + ((ua >> 16) & 1);
  ub += 0x7fff + ((ub >> 16) & 1);
  return (ua >> 16) | (ub & 0xffff0000u);
}
__device__ inline ushort f2bf(float f) {
  uint u = __float_as_uint(f);
  u += 0x7fff + ((u >> 16) & 1);
  return (ushort)(u >> 16);
}
__device__ inline float2 bf2f(uint v) {
  float2 r;
  r.x = __uint_as_float(v << 16);
  r.y = __uint_as_float(v & 0xffff0000u);
  return r;
}
__device__ inline uint relu2(uint u) {
  uint lo = (u & 0x8000u) ? 0u : (u & 0xFFFFu);
  uint hi = (u & 0x80000000u) ? 0u : (u & 0xFFFF0000u);
  return lo | hi;
}

// ---------------- prep: weight transposes (blocks 0..191) + bucket_count (192..703) ----------------
__global__ __launch_bounds__(256) void prep(const float* __restrict__ W1, uint* __restrict__ w1t,
                                            const float* __restrict__ W2, uint* __restrict__ w2t,
                                            const int* __restrict__ dst, int* __restrict__ cnt) {
  int b = blockIdx.x, t = threadIdx.x;
  if (b < 192) {
    __shared__ float col[256];
    const float* W; uint* Wt; int K, N, n;
    if (b < 128) { W = W1; Wt = w1t; K = 256; N = 128; n = b; }
    else         { W = W2; Wt = w2t; K = 128; N = 64;  n = b - 128; }
    if (t < K) col[t] = W[(size_t)t * N + n];
    __syncthreads();
    if (t < K / 2) Wt[(size_t)n * (K / 2) + t] = f2bf2(col[2 * t], col[2 * t + 1]);
  } else {
    __shared__ int h[NPARTS];
    int c = b - 192;
    for (int i = t; i < NPARTS; i += 256) h[i] = 0;
    __syncthreads();
    int beg = c * CE;
    for (int j = t; j < CE; j += 256) atomicAdd(&h[dst[beg + j] / PW], 1);
    __syncthreads();
    for (int i = t; i < NPARTS; i += 256) cnt[i * NCHUNKS + c] = h[i];
  }
}

// ---------------- scan (512-wide tiles; block-local exclusive; bsum added at consumer) ----------------
__global__ __launch_bounds__(512) void scan1(const int* __restrict__ in, int* __restrict__ out,
                                             int* __restrict__ bsum, int n) {
  __shared__ int s[512];
  int t = threadIdx.x;
  int i = blockIdx.x * 512 + t;
  int v = (i < n) ? in[i] : 0;
  s[t] = v;
  __syncthreads();
  for (int off = 1; off < 512; off <<= 1) {
    int add = (t >= off) ? s[t - off] : 0;
    __syncthreads();
    s[t] += add;
    __syncthreads();
  }
  if (i < n) out[i] = s[t] - v;
  if (t == 511) bsum[blockIdx.x] = s[511];
}

__global__ __launch_bounds__(512) void scan2(int* __restrict__ bsum, int nb) {
  __shared__ int s[512];
  int t = threadIdx.x;
  int v = (t < nb) ? bsum[t] : 0;
  s[t] = v;
  __syncthreads();
  for (int off = 1; off < 512; off <<= 1) {
    int add = (t >= off) ? s[t - off] : 0;
    __syncthreads();
    s[t] += add;
    __syncthreads();
  }
  if (t < nb) bsum[t] = s[t] - v;
}

// ---------------- bucket scatter (global offsets = off + bsum; tile = 512 -> idx>>9 = partition) ----------------
__global__ __launch_bounds__(512) void bucket_scatter(const int* __restrict__ src,
                                                      const int* __restrict__ dst,
                                                      const int* __restrict__ off,
                                                      const int* __restrict__ bsum,
                                                      uint* __restrict__ pk) {
  __shared__ int cur[NPARTS];
  int t = threadIdx.x, c = blockIdx.x;
  for (int i = t; i < NPARTS; i += 512) {
    int idx = i * NCHUNKS + c;
    cur[i] = off[idx] + bsum[idx >> 9];   // NCHUNKS==512 -> idx>>9 == i
  }
  __syncthreads();
  int beg = c * CE;
  for (int j = t; j < CE; j += 512) {
    int d = dst[beg + j];
    int p = d / PW;
    int pos = atomicAdd(&cur[p], 1);
    pk[pos] = (uint)src[beg + j] | ((uint)(d - p * PW) << 17);
  }
}

// ---------------- csr_finalize: 512 threads, single pk read (register-cached, static indices) ----------------
__global__ __launch_bounds__(512) void csr_finalize(const uint* __restrict__ pk,
                                                    const int* __restrict__ off,
                                                    const int* __restrict__ bsum,
                                                    int* __restrict__ row_off,
                                                    float* __restrict__ dinv,
                                                    int* __restrict__ csr) {
  __shared__ int hist[PW];
  __shared__ int cur[PW];
  __shared__ int s[512];
  int p = blockIdx.x, t = threadIdx.x;
  int base = off[p * NCHUNKS] + bsum[p];           // (p*NCHUNKS)>>9 == p
  int endp = NE;
  if (p < NPARTS - 1) endp = off[(p + 1) * NCHUNKS] + bsum[p + 1];
  if (t < PW) hist[t] = 0;
  __syncthreads();
  uint my[8];
#pragma unroll
  for (int u = 0; u < 8; ++u) {
    int j = base + t + u * 512;
    uint e = 0xFFFFFFFFu;
    if (j < endp) e = pk[j];
    my[u] = e;
    if (e != 0xFFFFFFFFu) atomicAdd(&hist[e >> 17], 1);
  }
  // safety fallback for spans > 4096 (mean 3200, sd ~57; never in practice)
  for (int j = base + t + 8 * 512; j < endp; j += 512) atomicAdd(&hist[pk[j] >> 17], 1);
  __syncthreads();
  int v = (t < PW) ? hist[t] : 0;
  s[t] = v;
  __syncthreads();
  for (int o = 1; o < 512; o <<= 1) {
    int add = (t >= o) ? s[t - o] : 0;
    __syncthreads();
    s[t] += add;
    __syncthreads();
  }
  if (t < PW) {
    int excl = base + (s[t] - v);
    int node = p * PW + t;
    row_off[node] = excl;
    dinv[node]    = rsqrtf((float)v + 1.0f);
    cur[t] = excl;
  }
  if (p == NPARTS - 1 && t == 0) row_off[NN] = NE;
  __syncthreads();
#pragma unroll
  for (int u = 0; u < 8; ++u) {
    uint e = my[u];
    if (e != 0xFFFFFFFFu) {
      int pos = atomicAdd(&cur[e >> 17], 1);
      csr[pos] = (int)(e & 0x1FFFFu);
    }
  }
  for (int j = base + t + 8 * 512; j < endp; j += 512) {
    uint e = pk[j];
    int pos = atomicAdd(&cur[e >> 17], 1);
    csr[pos] = (int)(e & 0x1FFFFu);
  }
}

// ---------------- barrier-free skinny MFMA GEMM ----------------
template<int K, int N, int WM, int WN, int A_BF16, int RELU>
__global__ __launch_bounds__(256) void gemm_direct(const void* __restrict__ Av,
                                                   const uint* __restrict__ Bt,
                                                   const float* __restrict__ dinv,
                                                   ushort* __restrict__ Cb, int M) {
  constexpr int NW = N / WN;     // cols per wave
  constexpr int NT = NW / 16;    // b-frags per wave
  __shared__ __align__(16) char bsm[N * K * 2];
  const int tid  = threadIdx.x;
  const int wid  = tid >> 6;
  const int lane = tid & 63;
  const int wm   = wid % WM;
  const int wn   = wid / WM;
  const int l15  = lane & 15;
  const int lk   = lane >> 4;
  const int blockRow = blockIdx.x * (WM * 32);

  constexpr int UPR = K / 8;        // uint4 per B row
  constexpr int TOT = N * K / 8;    // total uint4
#pragma unroll
  for (int i0 = 0; i0 < TOT; i0 += 256) {
    int i = i0 + tid;
    uint4 v = reinterpret_cast<const uint4*>(Bt)[i];
    int n = i / UPR, c = i % UPR;
    int byte = (n * (K * 2) + c * 16) ^ ((n & 7) << 4);
    *reinterpret_cast<uint4*>(bsm + byte) = v;
  }
  __syncthreads();

  f32x4 acc[2][NT];
#pragma unroll
  for (int i = 0; i < 2; ++i)
#pragma unroll
    for (int j = 0; j < NT; ++j) acc[i][j] = (f32x4){0.f, 0.f, 0.f, 0.f};

#pragma unroll
  for (int kk = 0; kk < K / 32; ++kk) {
    bf16x8 af[2], bfr[NT];
#pragma unroll
    for (int mt = 0; mt < 2; ++mt) {
      int grow = blockRow + wm * 32 + mt * 16 + l15;
      int row = grow < M ? grow : M - 1;
      if (A_BF16) {
        uint4 va = *reinterpret_cast<const uint4*>((const uint*)Av + (size_t)row * (K / 2) + kk * 16 + lk * 4);
        if (RELU) { va.x = relu2(va.x); va.y = relu2(va.y); va.z = relu2(va.z); va.w = relu2(va.w); }
        af[mt] = __builtin_bit_cast(bf16x8, va);
      } else {
        const float4* p = reinterpret_cast<const float4*>((const float*)Av + (size_t)row * K + kk * 32 + lk * 8);
        float4 f0 = p[0], f1 = p[1];
        uint4 va;
        va.x = f2bf2(f0.x, f0.y); va.y = f2bf2(f0.z, f0.w);
        va.z = f2bf2(f1.x, f1.y); va.w = f2bf2(f1.z, f1.w);
        af[mt] = __builtin_bit_cast(bf16x8, va);
      }
    }
#pragma unroll
    for (int nt = 0; nt < NT; ++nt) {
      int n = wn * NW + nt * 16 + l15;
      int byte = (n * (K * 2) + kk * 64 + lk * 16) ^ ((n & 7) << 4);
      bfr[nt] = __builtin_bit_cast(bf16x8, *reinterpret_cast<uint4*>(bsm + byte));
    }
#pragma unroll
    for (int mt = 0; mt < 2; ++mt)
#pragma unroll
      for (int nt = 0; nt < NT; ++nt)
        acc[mt][nt] = __builtin_amdgcn_mfma_f32_16x16x32_bf16(af[mt], bfr[nt], acc[mt][nt], 0, 0, 0);
  }

#pragma unroll
  for (int mt = 0; mt < 2; ++mt) {
    int rbase = blockRow + wm * 32 + mt * 16 + lk * 4;
#pragma unroll
    for (int j = 0; j < 4; ++j) {
      int grow = rbase + j;
      if (grow < M) {
        float d = dinv[grow];
#pragma unroll
        for (int nt = 0; nt < NT; ++nt) {
          int gcol = wn * NW + nt * 16 + l15;
          Cb[(size_t)grow * N + gcol] = f2bf(acc[mt][nt][j] * d);
        }
      }
    }
  }
}

// ---------------- conv1 agg: wave per node, 4 edge slots x 16 lanes x uint4 ----------------
__global__ __launch_bounds__(256) void agg_csr_f128_v2(const uint4* __restrict__ hs,
                                                       const float* __restrict__ dinv,
                                                       const float* __restrict__ bias,
                                                       const int* __restrict__ row_off,
                                                       const int* __restrict__ csr,
                                                       uint4* __restrict__ outb, int N) {
  int node = blockIdx.x * 4 + (threadIdx.x >> 6);
  if (node >= N) return;
  int lane = threadIdx.x & 63;
  int sl = lane >> 4;      // edge slot 0..3
  int c4 = lane & 15;      // uint4 column within row
  int beg = row_off[node], end = row_off[node + 1];
  float a0=0,a1=0,a2=0,a3=0,a4=0,a5=0,a6=0,a7=0;
  int j = beg;
  for (; j + 16 <= end; j += 16) {
    int s0 = csr[j + sl];
    int s1 = csr[j + 4 + sl];
    int s2 = csr[j + 8 + sl];
    int s3 = csr[j + 12 + sl];
    uint4 v0 = hs[(size_t)s0 * 16 + c4];
    uint4 v1 = hs[(size_t)s1 * 16 + c4];
    uint4 v2 = hs[(size_t)s2 * 16 + c4];
    uint4 v3 = hs[(size_t)s3 * 16 + c4];
    float2 f;
    f = bf2f(v0.x); a0+=f.x; a1+=f.y;  f = bf2f(v0.y); a2+=f.x; a3+=f.y;
    f = bf2f(v0.z); a4+=f.x; a5+=f.y;  f = bf2f(v0.w); a6+=f.x; a7+=f.y;
    f = bf2f(v1.x); a0+=f.x; a1+=f.y;  f = bf2f(v1.y); a2+=f.x; a3+=f.y;
    f = bf2f(v1.z); a4+=f.x; a5+=f.y;  f = bf2f(v1.w); a6+=f.x; a7+=f.y;
    f = bf2f(v2.x); a0+=f.x; a1+=f.y;  f = bf2f(v2.y); a2+=f.x; a3+=f.y;
    f = bf2f(v2.z); a4+=f.x; a5+=f.y;  f = bf2f(v2.w); a6+=f.x; a7+=f.y;
    f = bf2f(v3.x); a0+=f.x; a1+=f.y;  f = bf2f(v3.y); a2+=f.x; a3+=f.y;
    f = bf2f(v3.z); a4+=f.x; a5+=f.y;  f = bf2f(v3.w); a6+=f.x; a7+=f.y;
  }
  for (; j + 4 <= end; j += 4) {
    int s0 = csr[j + sl];
    uint4 v0 = hs[(size_t)s0 * 16 + c4];
    float2 f;
    f = bf2f(v0.x); a0+=f.x; a1+=f.y;  f = bf2f(v0.y); a2+=f.x; a3+=f.y;
    f = bf2f(v0.z); a4+=f.x; a5+=f.y;  f = bf2f(v0.w); a6+=f.x; a7+=f.y;
  }
  if (j + sl < end) {
    int s0 = csr[j + sl];
    uint4 v0 = hs[(size_t)s0 * 16 + c4];
    float2 f;
    f = bf2f(v0.x); a0+=f.x; a1+=f.y;  f = bf2f(v0.y); a2+=f.x; a3+=f.y;
    f = bf2f(v0.z); a4+=f.x; a5+=f.y;  f = bf2f(v0.w); a6+=f.x; a7+=f.y;
  }
  a0 += __shfl_xor(a0, 16); a1 += __shfl_xor(a1, 16); a2 += __shfl_xor(a2, 16); a3 += __shfl_xor(a3, 16);
  a4 += __shfl_xor(a4, 16); a5 += __shfl_xor(a5, 16); a6 += __shfl_xor(a6, 16); a7 += __shfl_xor(a7, 16);
  a0 += __shfl_xor(a0, 32); a1 += __shfl_xor(a1, 32); a2 += __shfl_xor(a2, 32); a3 += __shfl_xor(a3, 32);
  a4 += __shfl_xor(a4, 32); a5 += __shfl_xor(a5, 32); a6 += __shfl_xor(a6, 32); a7 += __shfl_xor(a7, 32);
  if (sl == 0) {
    uint4 v = hs[(size_t)node * 16 + c4];  // self
    float2 f;
    f = bf2f(v.x); a0+=f.x; a1+=f.y;  f = bf2f(v.y); a2+=f.x; a3+=f.y;
    f = bf2f(v.z); a4+=f.x; a5+=f.y;  f = bf2f(v.w); a6+=f.x; a7+=f.y;
    float d = dinv[node];
    const float4* bp = reinterpret_cast<const float4*>(bias);
    float4 b0 = bp[c4 * 2], b1 = bp[c4 * 2 + 1];
    uint4 o;
    o.x = f2bf2(fmaf(a0, d, b0.x), fmaf(a1, d, b0.y));
    o.y = f2bf2(fmaf(a2, d, b0.z), fmaf(a3, d, b0.w));
    o.z = f2bf2(fmaf(a4, d, b1.x), fmaf(a5, d, b1.y));
    o.w = f2bf2(fmaf(a6, d, b1.z), fmaf(a7, d, b1.w));
    outb[(size_t)node * 16 + c4] = o;
  }
}

// ---------------- conv2 agg: wave per node, 8 edge slots x 8 lanes x uint4, bf16 out ----------------
__global__ __launch_bounds__(256) void agg_csr_f64_v3(const uint4* __restrict__ hs,
                                                      const float* __restrict__ dinv,
                                                      const int* __restrict__ row_off,
                                                      const int* __restrict__ csr,
                                                      uint4* __restrict__ outb, int N) {
  int node = blockIdx.x * 4 + (threadIdx.x >> 6);
  if (node >= N) return;
  int lane = threadIdx.x & 63;
  int sl = lane >> 3;      // edge slot 0..7
  int c4 = lane & 7;       // uint4 column
  int beg = row_off[node], end = row_off[node + 1];
  float a0=0,a1=0,a2=0,a3=0,a4=0,a5=0,a6=0,a7=0;
  int j = beg;
  for (; j + 16 <= end; j += 16) {
    int s0 = csr[j + sl];
    int s1 = csr[j + 8 + sl];
    uint4 v0 = hs[(size_t)s0 * 8 + c4];
    uint4 v1 = hs[(size_t)s1 * 8 + c4];
    float2 f;
    f = bf2f(v0.x); a0+=f.x; a1+=f.y;  f = bf2f(v0.y); a2+=f.x; a3+=f.y;
    f = bf2f(v0.z); a4+=f.x; a5+=f.y;  f = bf2f(v0.w); a6+=f.x; a7+=f.y;
    f = bf2f(v1.x); a0+=f.x; a1+=f.y;  f = bf2f(v1.y); a2+=f.x; a3+=f.y;
    f = bf2f(v1.z); a4+=f.x; a5+=f.y;  f = bf2f(v1.w); a6+=f.x; a7+=f.y;
  }
  for (; j + 8 <= end; j += 8) {
    int s0 = csr[j + sl];
    uint4 v0 = hs[(size_t)s0 * 8 + c4];
    float2 f;
    f = bf2f(v0.x); a0+=f.x; a1+=f.y;  f = bf2f(v0.y); a2+=f.x; a3+=f.y;
    f = bf2f(v0.z); a4+=f.x; a5+=f.y;  f = bf2f(v0.w); a6+=f.x; a7+=f.y;
  }
  if (j + sl < end) {
    int s0 = csr[j + sl];
    uint4 v0 = hs[(size_t)s0 * 8 + c4];
    float2 f;
    f = bf2f(v0.x); a0+=f.x; a1+=f.y;  f = bf2f(v0.y); a2+=f.x; a3+=f.y;
    f = bf2f(v0.z); a4+=f.x; a5+=f.y;  f = bf2f(v0.w); a6+=f.x; a7+=f.y;
  }
  a0 += __shfl_xor(a0, 8);  a1 += __shfl_xor(a1, 8);  a2 += __shfl_xor(a2, 8);  a3 += __shfl_xor(a3, 8);
  a4 += __shfl_xor(a4, 8);  a5 += __shfl_xor(a5, 8);  a6 += __shfl_xor(a6, 8);  a7 += __shfl_xor(a7, 8);
  a0 += __shfl_xor(a0, 16); a1 += __shfl_xor(a1, 16); a2 += __shfl_xor(a2, 16); a3 += __shfl_xor(a3, 16);
  a4 += __shfl_xor(a4, 16); a5 += __shfl_xor(a5, 16); a6 += __shfl_xor(a6, 16); a7 += __shfl_xor(a7, 16);
  a0 += __shfl_xor(a0, 32); a1 += __shfl_xor(a1, 32); a2 += __shfl_xor(a2, 32); a3 += __shfl_xor(a3, 32);
  a4 += __shfl_xor(a4, 32); a5 += __shfl_xor(a5, 32); a6 += __shfl_xor(a6, 32); a7 += __shfl_xor(a7, 32);
  if (sl == 0) {
    uint4 v = hs[(size_t)node * 8 + c4];  // self
    float2 f;
    f = bf2f(v.x); a0+=f.x; a1+=f.y;  f = bf2f(v.y); a2+=f.x; a3+=f.y;
    f = bf2f(v.z); a4+=f.x; a5+=f.y;  f = bf2f(v.w); a6+=f.x; a7+=f.y;
    float d = dinv[node];
    uint4 o;
    o.x = f2bf2(a0 * d, a1 * d);
    o.y = f2bf2(a2 * d, a3 * d);
    o.z = f2bf2(a4 * d, a5 * d);
    o.w = f2bf2(a6 * d, a7 * d);
    outb[(size_t)node * 8 + c4] = o;
  }
}

// ---------------- fused per-graph mean pool (bf16 in) + MLP (adds deferred b2) ----------------
__global__ __launch_bounds__(256) void pool_mlp(const uint* __restrict__ hb,
                                                const int* __restrict__ batch,
                                                const float* __restrict__ scalars,
                                                const float* __restrict__ b2,
                                                const float* __restrict__ W3,
                                                const float* __restrict__ b3,
                                                const float* __restrict__ W4,
                                                const float* __restrict__ b4,
                                                float* __restrict__ out, int N) {
  int g = blockIdx.x;
  int t = threadIdx.x;  // 256
  int c = t & 31, rr = t >> 5;   // 8 row-groups x 32 packed cols
  __shared__ int range[2];
  __shared__ float2 part[8][32];
  __shared__ float comb[66];
  __shared__ float red[2];
  if (t < 2) {
    int target = g + t;
    int lo = 0, hi = N;
    while (lo < hi) { int mid = (lo + hi) >> 1; if (batch[mid] < target) lo = mid + 1; else hi = mid; }
    range[t] = lo;
  }
  __syncthreads();
  int beg = range[0], end = range[1];
  float sx = 0.f, sy = 0.f;
  for (int i = beg + rr; i < end; i += 8) {
    float2 f = bf2f(hb[(size_t)i * 32 + c]);
    sx += f.x; sy += f.y;
  }
  part[rr][c] = make_float2(sx, sy);
  __syncthreads();
  if (rr == 0) {
    float tx = 0.f, ty = 0.f;
#pragma unroll
    for (int r = 0; r < 8; ++r) { tx += part[r][c].x; ty += part[r][c].y; }
    float cnt = fmaxf((float)(end - beg), 1.f);
    comb[2 * c]     = tx / cnt + b2[2 * c];
    comb[2 * c + 1] = ty / cnt + b2[2 * c + 1];
  } else if (t == 64 || t == 65) {
    comb[t] = scalars[g * 2 + (t - 64)];
  }
  __syncthreads();
  if (t < 128) {
    float hh = b3[t];
#pragma unroll
    for (int k = 0; k < 66; ++k) hh += comb[k] * W3[k * 128 + t];
    hh = fmaxf(hh, 0.f);
    float p = hh * W4[t];
#pragma unroll
    for (int off = 32; off > 0; off >>= 1) p += __shfl_down(p, off);
    if ((t & 63) == 0) red[t >> 6] = p;
  }
  __syncthreads();
  if (t == 0) {
    float sum = red[0] + red[1] + b4[0];
    out[g] = 1.f / (1.f + expf(-sum));
  }
}

extern "C" void kernel_launch(void* const* d_in, const int* in_sizes, int n_in,
                              void* d_out, int out_size, void* d_ws, size_t ws_size,
                              hipStream_t stream) {
  const float* x       = (const float*)d_in[0];
  const int*   ei      = (const int*)d_in[1];
  const int*   src     = ei;
  const int*   dstp    = ei + NE;
  const int*   batch   = (const int*)d_in[2];
  const float* scalars = (const float*)d_in[3];
  const float* W1 = (const float*)d_in[4];  const float* b1 = (const float*)d_in[5];
  const float* W2 = (const float*)d_in[6];  const float* b2 = (const float*)d_in[7];
  const float* W3 = (const float*)d_in[8];  const float* b3 = (const float*)d_in[9];
  const float* W4 = (const float*)d_in[10]; const float* b4 = (const float*)d_in[11];
  float* out = (float*)d_out;

  // workspace layout (32-bit words) — 16B-aligned segments first
  uint*  ws      = (uint*)d_ws;
  uint*  w1t     = ws;                      // [128*128]  (W1^T bf16)
  uint*  w2t     = ws + 16384;              // [64*64]    (W2^T bf16)
  uint*  hsb     = ws + 20480;              // [100000,64]u bf16 hs; reused [100000,32]u
  uint*  agg1b   = hsb + 6400000;           // [100000,64]u bf16 agg1; reused agg2 bf16 [100000,32]u
  float* dinv    = (float*)(agg1b + 6400000); // [100000]
  int*   row_off = (int*)(dinv + NN);       // [100004] (padded)
  int*   csr     = row_off + NN + 4;        // [1600000]
  uint*  pk      = (uint*)(csr + NE);       // [1600000]
  int*   cnt     = (int*)(pk + NE);         // [256000]
  int*   bsum    = cnt + NCNT;              // [512]

  // prep: weight transposes + bucket counts (independent, one launch)
  prep<<<704, 256, 0, stream>>>(W1, w1t, W2, w2t, dstp, cnt);

  // CSR build (no global atomics)
  scan1<<<(NCNT + 511) / 512, 512, 0, stream>>>(cnt, cnt, bsum, NCNT);
  scan2<<<1, 512, 0, stream>>>(bsum, (NCNT + 511) / 512);
  bucket_scatter<<<NCHUNKS, 512, 0, stream>>>(src, dstp, cnt, bsum, pk);
  csr_finalize<<<NPARTS, 512, 0, stream>>>(pk, cnt, bsum, row_off, dinv, csr);

  // conv1: hsb = bf16((x @ W1) * dinv) ; agg1b = bf16(dinv*(gather+self) + b1)
  gemm_direct<256, 128, 4, 1, 0, 0><<<(NN + 127) / 128, 256, 0, stream>>>(
      x, w1t, dinv, (ushort*)hsb, NN);
  agg_csr_f128_v2<<<(NN + 3) / 4, 256, 0, stream>>>((const uint4*)hsb, dinv, b1,
                                                    row_off, csr, (uint4*)agg1b, NN);

  // conv2: hsb = bf16((relu(agg1b) @ W2) * dinv) ; agg2 = bf16(dinv*(gather+self)) (b2 deferred)
  gemm_direct<128, 64, 4, 1, 1, 1><<<(NN + 127) / 128, 256, 0, stream>>>(
      agg1b, w2t, dinv, (ushort*)hsb, NN);
  agg_csr_f64_v3<<<(NN + 3) / 4, 256, 0, stream>>>((const uint4*)hsb, dinv,
                                                   row_off, csr, (uint4*)agg1b, NN);

  // fused pool + MLP (b2 added here)
  pool_mlp<<<NG, 256, 0, stream>>>(agg1b, batch, scalars, b2,
                                   W3, b3, W4, b4, out, NN);
}